// Round 12
// baseline (172.060 us; speedup 1.0000x reference)
//
#include <hip/hip_runtime.h>
#include <stdint.h>

typedef unsigned short u16;
typedef __attribute__((ext_vector_type(8))) short short8;
typedef __attribute__((ext_vector_type(4))) float f32x4;

#define Bn 16
#define Kn 36
#define Cn 2048
#define Qn 1024
#define LINn 1024
#define NPp 1296      // 36*36 pairs per batch
#define NPAIRn 20736  // 16*1296
#define NBIn 576      // 16*36

__device__ __forceinline__ u16 f2bf(float f) {
  union { float f; unsigned int u; } v; v.f = f;
  unsigned int r = v.u + 0x7FFFu + ((v.u >> 16) & 1u);
  return (u16)(r >> 16);
}

__device__ __forceinline__ void llds16(const void* g, void* l) {
  __builtin_amdgcn_global_load_lds((const __attribute__((address_space(1))) void*)g,
                                   (__attribute__((address_space(3))) void*)l, 16, 0, 0);
}

// All four weight transposes in one launch. grid (32,64,4), block 256.
__global__ void k_transpose_all(const float* __restrict__ W1, const float* __restrict__ W2,
                                const float* __restrict__ W3, u16* __restrict__ W1abT,
                                u16* __restrict__ W2T, u16* __restrict__ W3T) {
  __shared__ float tile[32][33];
  int z = blockIdx.z;
  const float* src; u16* dst; int ld_dst;
  if (z == 0)      { if (blockIdx.y >= 32) return; src = W2; dst = W2T; ld_dst = 1024; }
  else if (z == 1) { if (blockIdx.y >= 32) return; src = W3; dst = W3T; ld_dst = 1024; }
  else if (z == 2) { src = W1; dst = W1abT; ld_dst = 2048; }
  else             { src = W1 + (size_t)2048 * 1024; dst = W1abT + (size_t)1024 * 2048; ld_dst = 2048; }
  int n0 = blockIdx.x * 32, k0 = blockIdx.y * 32;
  int tx = threadIdx.x & 31, ty = threadIdx.x >> 5;  // 32x8
#pragma unroll
  for (int r = 0; r < 32; r += 8)
    tile[ty + r][tx] = src[(size_t)(k0 + ty + r) * 1024 + (n0 + tx)];
  __syncthreads();
#pragma unroll
  for (int r = 0; r < 32; r += 8)
    dst[(size_t)(n0 + ty + r) * ld_dst + (k0 + tx)] = f2bf(tile[tx][ty + r]);
}

__global__ void k_f2b(const float4* __restrict__ src, ushort4* __restrict__ dst, int n4) {
  int i = blockIdx.x * 256 + threadIdx.x;
  if (i < n4) {
    float4 v = src[i];
    ushort4 o;
    o.x = f2bf(v.x); o.y = f2bf(v.y); o.z = f2bf(v.z); o.w = f2bf(v.w);
    dst[i] = o;
  }
}

// Build compacted valid-pair list. grid 16 (one block per batch), 256 threads.
__global__ void k_build(const int* __restrict__ index, int* __restrict__ pairList,
                        int* __restrict__ batchC, int* __restrict__ cnt2) {
  __shared__ int offs[17];
  int tid = threadIdx.x;
  int b = blockIdx.x;
  if (tid == 0) {
    int o = 0;
    for (int i = 0; i < Bn; ++i) { offs[i] = o; int v = index[i]; o += v * v; }
    offs[16] = o;
    if (b == 0) {
      cnt2[0] = o;
      cnt2[1] = (o + 127) & ~127;
    }
  }
  __syncthreads();
  int v = index[b]; int n = v * v; int base = offs[b];
  for (int t = tid; t < n; t += 256) {
    int i = t / v, j = t - i * v;
    pairList[base + t] = b * NPp + i * Kn + j;
    batchC[base + t] = b;
  }
  if (b == 0) {
    int total = offs[16];
    int totalPad = (total + 255) & ~255;
    for (int t = total + tid; t < totalPad; t += 256) {
      pairList[t] = 0;
      batchC[t] = 0;
    }
  }
}

// Pc[b][n] = b1[n]  (init for atomic accumulation). grid 4, block 256.
__global__ void k_pcinit(const float* __restrict__ b1, float* __restrict__ Pc) {
  int n = blockIdx.x * 256 + threadIdx.x;
  float v = b1[n];
#pragma unroll
  for (int b = 0; b < Bn; ++b) Pc[b * LINn + n] = v;
}

// Pc[b][n] += sum_k q[b][k]*Wq[k][n], Wq streamed once. grid (4 nblk, 32 kz), block 256.
__global__ void k_pconst(const float* __restrict__ q, const float* __restrict__ W1,
                         float* __restrict__ Pc) {
  __shared__ float qs[Bn][32];
  int n = blockIdx.x * 256 + threadIdx.x;
  int k0 = blockIdx.y * 32;
  const float* Wq = W1 + (size_t)(2 * Cn) * LINn;
  for (int t = threadIdx.x; t < Bn * 32; t += 256) {
    int b = t >> 5, k = t & 31;
    qs[b][k] = q[b * Qn + k0 + k];
  }
  __syncthreads();
  float acc[Bn];
#pragma unroll
  for (int b = 0; b < Bn; ++b) acc[b] = 0.f;
  for (int k = 0; k < 32; ++k) {
    float w = Wq[(size_t)(k0 + k) * LINn + n];
#pragma unroll
    for (int b = 0; b < Bn; ++b) acc[b] += qs[b][k] * w;
  }
#pragma unroll
  for (int b = 0; b < Bn; ++b) atomicAdd(&Pc[b * LINn + n], acc[b]);
}

// per-compacted-pair scalars. 1 wave per pair, 4 waves/block, grid-stride.
__global__ void k_pairscalars(const float* __restrict__ bfm, const float* __restrict__ bc,
                              const int* __restrict__ pairList, const int* __restrict__ cnt2,
                              float* __restrict__ dotC, float* __restrict__ iouC,
                              float* __restrict__ oijC, float* __restrict__ ojiC) {
  int cnt = cnt2[0];
  int lane = threadIdx.x & 63;
  for (int m = blockIdx.x * 4 + (threadIdx.x >> 6); m < cnt; m += gridDim.x * 4) {
    int p = pairList[m];
    int b = p / NPp, rem = p - b * NPp, i = rem / Kn, j = rem - (rem / Kn) * Kn;
    const float4* Ai = (const float4*)(bfm + (size_t)(b * Kn + i) * Cn);
    const float4* Aj = (const float4*)(bfm + (size_t)(b * Kn + j) * Cn);
    float s = 0.f;
#pragma unroll
    for (int t = 0; t < Cn / 4 / 64; ++t) {
      float4 x = Ai[lane + t * 64], y = Aj[lane + t * 64];
      s += x.x * y.x + x.y * y.y + x.z * y.z + x.w * y.w;
    }
#pragma unroll
    for (int o = 32; o > 0; o >>= 1) s += __shfl_down(s, o);
    if (lane == 0) {
      const float* ci = bc + (size_t)(b * Kn + i) * 6;
      const float* cj = bc + (size_t)(b * Kn + j) * 6;
      float ai = (ci[2] - ci[0]) * (ci[3] - ci[1]);
      float aj = (cj[2] - cj[0]) * (cj[3] - cj[1]);
      float lr = fmaxf(0.f, fminf(ci[2], cj[2]) - fmaxf(ci[0], cj[0]));
      float ud = fmaxf(0.f, fminf(ci[3], cj[3]) - fmaxf(ci[1], cj[1]));
      float ov = lr * ud;
      dotC[m] = s;
      iouC[m] = ov / (ai + aj - ov);
      oijC[m] = ov / ai;
      ojiC[m] = ov / aj;
    }
  }
}

// P12 init: P12[bi][c] = bc rank-1 terms + (c<1024 ? Pc[b][c] : 0).
__global__ void k_pinit(const float* __restrict__ Pc, const float* __restrict__ bc,
                        const float* __restrict__ W1, float* __restrict__ P12) {
  int bi = blockIdx.x;
  int b = bi / Kn;
  const float* c = bc + (size_t)bi * 6;
  const float* W = W1 + (size_t)(2 * Cn + Qn + 1) * LINn;  // row 5121
#pragma unroll
  for (int it = 0; it < 8; ++it) {
    int cc = it * 256 + threadIdx.x;  // 0..2047
    int n = cc & 1023;
    int rbase = (cc < 1024) ? 0 : 6;
    float a = 0.f;
#pragma unroll
    for (int t = 0; t < 6; ++t) a += c[t] * W[(size_t)(rbase + t) * LINn + n];
    if (cc < 1024) a += Pc[b * LINn + n];
    P12[(size_t)bi * 2048 + cc] = a;
  }
}

// H1[m][n] = relu(P1'[b,i][n] + P2[b,j][n] + d*wd + u*wu + o1*wa + o2*wb) -> bf16
__global__ void k_h1(const float* __restrict__ P12,
                     const float* __restrict__ dotC, const float* __restrict__ iouC,
                     const float* __restrict__ oijC, const float* __restrict__ ojiC,
                     const int* __restrict__ pairList, const int* __restrict__ cnt2,
                     const float* __restrict__ W1, u16* __restrict__ H1) {
  int cnt = cnt2[0];
  int t = threadIdx.x;
  const float4* wd = (const float4*)(W1 + (size_t)(2 * Cn + Qn) * LINn);       // 5120
  const float4* wu = (const float4*)(W1 + (size_t)(2 * Cn + Qn + 13) * LINn);  // 5133
  const float4* wa = (const float4*)(W1 + (size_t)(2 * Cn + Qn + 14) * LINn);  // 5134
  const float4* wb = (const float4*)(W1 + (size_t)(2 * Cn + Qn + 15) * LINn);  // 5135
  float4 e1 = wd[t], e2 = wu[t], e3 = wa[t], e4 = wb[t];
  for (int m = blockIdx.x; m < cnt; m += gridDim.x) {
    int p = pairList[m];
    int b = p / NPp, rem = p - b * NPp, i = rem / Kn, j = rem - (rem / Kn) * Kn;
    float d = dotC[m], u = iouC[m], o1 = oijC[m], o2 = ojiC[m];
    const float4* p1 = (const float4*)(P12 + (size_t)(b * Kn + i) * 2048);
    const float4* p2 = (const float4*)(P12 + (size_t)(b * Kn + j) * 2048 + 1024);
    ushort4* outp = (ushort4*)(H1 + (size_t)m * 1024);
    float4 v1 = p1[t], v2 = p2[t];
    ushort4 o;
    o.x = f2bf(fmaxf(v1.x + v2.x + d * e1.x + u * e2.x + o1 * e3.x + o2 * e4.x, 0.f));
    o.y = f2bf(fmaxf(v1.y + v2.y + d * e1.y + u * e2.y + o1 * e3.y + o2 * e4.y, 0.f));
    o.z = f2bf(fmaxf(v1.z + v2.z + d * e1.z + u * e2.z + o1 * e3.z + o2 * e4.z, 0.f));
    o.w = f2bf(fmaxf(v1.w + v2.w + d * e1.w + u * e2.w + o1 * e3.w + o2 * e4.w, 0.f));
    outp[t] = o;
  }
}

// P-GEMM: 128x64 tile, BK=64, 2-buffer counted vmcnt, atomicAdd into P12.
__global__ void __launch_bounds__(256) k_gemmP(
    const u16* __restrict__ A, const u16* __restrict__ BT,
    int N, int K, int KC, int Mvalid,
    float* __restrict__ Cf) {
  __shared__ u16 Alds[2][128 * 64];
  __shared__ u16 Blds[2][64 * 64];
  const int tid = threadIdx.x;
  const int wave = tid >> 6, lane = tid & 63;
  const int wm = (wave >> 1) * 64, wn = (wave & 1) * 32;
  const int m0 = blockIdx.x * 128;
  const int n0 = blockIdx.y * 64;
  const int Mv = Mvalid;

  f32x4 zero = {0.f, 0.f, 0.f, 0.f};
  f32x4 acc[4][2];
#pragma unroll
  for (int x = 0; x < 4; ++x)
#pragma unroll
    for (int y = 0; y < 2; ++y) acc[x][y] = zero;

  const int srow = tid >> 3;
  const int sslot = ((tid & 7) ^ (srow & 7)) * 16;
  const size_t ldb = (size_t)K * 2;

  auto stage = [&](int buf, int k0) {
    char* aB = (char*)Alds[buf] + wave * 1024;
    char* bB = (char*)Blds[buf] + wave * 1024;
#pragma unroll
    for (int c = 0; c < 4; ++c) {
      int rg = m0 + c * 32 + srow; if (rg >= Mv) rg = Mv - 1;
      llds16((const char*)A + (size_t)rg * ldb + (size_t)k0 * 2 + sslot, aB + c * 4096);
    }
#pragma unroll
    for (int c = 0; c < 2; ++c) {
      int rg = n0 + c * 32 + srow;
      llds16((const char*)BT + (size_t)rg * ldb + (size_t)k0 * 2 + sslot, bB + c * 4096);
    }
  };

  auto compute = [&](int buf) {
    const char* Ab = (const char*)Alds[buf];
    const char* Bb = (const char*)Blds[buf];
    short8 af[2][4], bfr[2][2];
#pragma unroll
    for (int kk = 0; kk < 2; ++kk) {
#pragma unroll
      for (int f = 0; f < 4; ++f) {
        int rA = wm + f * 16 + (lane & 15);
        int sl = ((kk * 4 + (lane >> 4)) ^ (rA & 7)) * 16;
        af[kk][f] = *(const short8*)(Ab + (size_t)rA * 128 + sl);
      }
#pragma unroll
      for (int f = 0; f < 2; ++f) {
        int rB = wn + f * 16 + (lane & 15);
        int sl = ((kk * 4 + (lane >> 4)) ^ (rB & 7)) * 16;
        bfr[kk][f] = *(const short8*)(Bb + (size_t)rB * 128 + sl);
      }
    }
#pragma unroll
    for (int kk = 0; kk < 2; ++kk)
#pragma unroll
      for (int x = 0; x < 4; ++x)
#pragma unroll
        for (int y = 0; y < 2; ++y)
          acc[x][y] = __builtin_amdgcn_mfma_f32_16x16x32_bf16(af[kk][x], bfr[kk][y],
                                                              acc[x][y], 0, 0, 0);
  };

  const int kbeg = blockIdx.z * KC;
  const int nt = KC >> 6;
  stage(0, kbeg);
  for (int t = 0; t < nt; ++t) {
    if (t + 1 < nt) {
      stage((t + 1) & 1, kbeg + (t + 1) * 64);
      asm volatile("s_waitcnt vmcnt(6)" ::: "memory");
    } else {
      asm volatile("s_waitcnt vmcnt(0)" ::: "memory");
    }
    __builtin_amdgcn_s_barrier();
    compute(t & 1);
    __builtin_amdgcn_s_barrier();
  }

#pragma unroll
  for (int x = 0; x < 4; ++x) {
    int rb = m0 + wm + x * 16 + (lane >> 4) * 4;
#pragma unroll
    for (int r = 0; r < 4; ++r) {
      int row = rb + r;
      if (row < Mv) {
#pragma unroll
        for (int y = 0; y < 2; ++y)
          atomicAdd(&Cf[(size_t)row * N + (n0 + wn + y * 16 + (lane & 15))],
                    acc[x][y][r]);
      }
    }
  }
}

// 256x256-tile bf16 MFMA GEMM, 8 waves (2M x 4N, each 128x64, acc[8][4] -> 64
// MFMA/wave/K-step), BK=64, 2-buffer counted-vmcnt, 128 KB LDS (1 block/CU).
// Per-wave arithmetic intensity 4x the 128x64 kernel: amortizes the 2-phase
// per-step fixed cost. XOR-swizzle slot^=row&7 both sides (rule 21).
// EPI 1: relu(acc+bias) -> bf16. EPI 2: masked per-batch reduce into G
// (Gpart aliases A-LDS after the K-loop).
template <int EPI>
__global__ void __launch_bounds__(512, 2) k_gemm2(
    const u16* __restrict__ A, const u16* __restrict__ BT,
    const int* __restrict__ cnt2,
    u16* __restrict__ Cb, const float* __restrict__ bias,
    const int* __restrict__ batchC, float* __restrict__ G) {
  __shared__ u16 Alds[2][256 * 64];   // 2 x 32 KB
  __shared__ u16 Blds[2][256 * 64];   // 2 x 32 KB

  const int tid = threadIdx.x;
  const int wave = tid >> 6, lane = tid & 63;
  const int wm = (wave >> 2) * 128;    // 0 / 128
  const int wn = (wave & 3) * 64;      // 0 / 64 / 128 / 192

  const int cnt = cnt2[0];
  const int nMt = (cnt + 255) >> 8;
  const int nact = nMt * 4;            // 4 N-tiles of 256
  int id = blockIdx.x;
  if (id >= nact) return;
  int q = nact >> 3, r = nact & 7;
  int xcd = id & 7, rank = id >> 3;
  int wg = (xcd < r ? xcd * (q + 1) : r * (q + 1) + (xcd - r) * q) + rank;
  const int m0 = (wg >> 2) * 256;
  const int n0 = (wg & 3) * 256;

  f32x4 zero = {0.f, 0.f, 0.f, 0.f};
  f32x4 acc[8][4];
#pragma unroll
  for (int x = 0; x < 8; ++x)
#pragma unroll
    for (int y = 0; y < 4; ++y) acc[x][y] = zero;

  // staging: 512 threads cover 64 rows x 8 slots per round; 4 rounds each A,B.
  const int srow = tid >> 3;                          // 0..63
  const int sslot = ((tid & 7) ^ (srow & 7)) * 16;
  const size_t ldb = (size_t)1024 * 2;

  auto stage = [&](int buf, int k0) {
    char* aB = (char*)Alds[buf] + srow * 128 + (tid & 7) * 16;
    char* bB = (char*)Blds[buf] + srow * 128 + (tid & 7) * 16;
#pragma unroll
    for (int c = 0; c < 4; ++c) {
      int rg = m0 + c * 64 + srow; if (rg >= cnt) rg = cnt - 1;
      llds16((const char*)A + (size_t)rg * ldb + (size_t)k0 * 2 + sslot, aB + c * 8192);
    }
#pragma unroll
    for (int c = 0; c < 4; ++c) {
      int rg = n0 + c * 64 + srow;
      llds16((const char*)BT + (size_t)rg * ldb + (size_t)k0 * 2 + sslot, bB + c * 8192);
    }
  };

  auto compute = [&](int buf) {
    const char* Ab = (const char*)Alds[buf];
    const char* Bb = (const char*)Blds[buf];
#pragma unroll
    for (int kk = 0; kk < 2; ++kk) {
      short8 af[8], bfr[4];
#pragma unroll
      for (int f = 0; f < 8; ++f) {
        int rA = wm + f * 16 + (lane & 15);
        int sl = ((kk * 4 + (lane >> 4)) ^ (rA & 7)) * 16;
        af[f] = *(const short8*)(Ab + (size_t)rA * 128 + sl);
      }
#pragma unroll
      for (int f = 0; f < 4; ++f) {
        int rB = wn + f * 16 + (lane & 15);
        int sl = ((kk * 4 + (lane >> 4)) ^ (rB & 7)) * 16;
        bfr[f] = *(const short8*)(Bb + (size_t)rB * 128 + sl);
      }
#pragma unroll
      for (int x = 0; x < 8; ++x)
#pragma unroll
        for (int y = 0; y < 4; ++y)
          acc[x][y] = __builtin_amdgcn_mfma_f32_16x16x32_bf16(af[x], bfr[y],
                                                              acc[x][y], 0, 0, 0);
    }
  };

  const int nt = 16;  // K=1024, BK=64
  stage(0, 0);
  for (int t = 0; t < nt; ++t) {
    if (t + 1 < nt) {
      stage((t + 1) & 1, (t + 1) * 64);
      asm volatile("s_waitcnt vmcnt(8)" ::: "memory");  // tile t landed; t+1 in flight
    } else {
      asm volatile("s_waitcnt vmcnt(0)" ::: "memory");
    }
    __builtin_amdgcn_s_barrier();
    compute(t & 1);
    __builtin_amdgcn_s_barrier();
  }

  if (EPI == 1) {
#pragma unroll
    for (int x = 0; x < 8; ++x) {
      int rb = m0 + wm + x * 16 + (lane >> 4) * 4;
#pragma unroll
      for (int r = 0; r < 4; ++r) {
        int row = rb + r;
#pragma unroll
        for (int y = 0; y < 4; ++y) {
          int col = n0 + wn + y * 16 + (lane & 15);
          Cb[(size_t)row * 1024 + col] = f2bf(fmaxf(acc[x][y][r] + bias[col], 0.f));
        }
      }
    }
  } else {
    // Gpart aliases A-LDS (free after the K-loop's final barrier).
    float* Gpart = (float*)&Alds[0][0];   // 16 x 256 fp32 = 16 KB
    for (int t2 = tid; t2 < Bn * 256; t2 += 512) Gpart[t2] = 0.f;
    __syncthreads();
#pragma unroll
    for (int x = 0; x < 8; ++x) {
      int rb = m0 + wm + x * 16 + (lane >> 4) * 4;
      int rc0 = (rb     < cnt) ? rb     : (cnt - 1);
      int rc1 = (rb + 1 < cnt) ? rb + 1 : (cnt - 1);
      int rc2 = (rb + 2 < cnt) ? rb + 2 : (cnt - 1);
      int rc3 = (rb + 3 < cnt) ? rb + 3 : (cnt - 1);
      int b0 = batchC[rc0], b1 = batchC[rc1], b2 = batchC[rc2], b3 = batchC[rc3];
      float mk0 = (rb     < cnt) ? 1.f : 0.f;
      float mk1 = (rb + 1 < cnt) ? 1.f : 0.f;
      float mk2 = (rb + 2 < cnt) ? 1.f : 0.f;
      float mk3 = (rb + 3 < cnt) ? 1.f : 0.f;
#pragma unroll
      for (int y = 0; y < 4; ++y) {
        int coll = wn + y * 16 + (lane & 15);
        float bs = bias[n0 + coll];
        float s0 = mk0 * fmaxf(acc[x][y][0] + bs, 0.f);
        float s1 = mk1 * fmaxf(acc[x][y][1] + bs, 0.f);
        float s2 = mk2 * fmaxf(acc[x][y][2] + bs, 0.f);
        float s3 = mk3 * fmaxf(acc[x][y][3] + bs, 0.f);
        if (b0 == b3) {
          atomicAdd(&Gpart[b0 * 256 + coll], s0 + s1 + s2 + s3);
        } else {
          atomicAdd(&Gpart[b0 * 256 + coll], s0);
          atomicAdd(&Gpart[b1 * 256 + coll], s1);
          atomicAdd(&Gpart[b2 * 256 + coll], s2);
          atomicAdd(&Gpart[b3 * 256 + coll], s3);
        }
      }
    }
    __syncthreads();
    for (int t2 = tid; t2 < Bn * 256; t2 += 512) {
      float v = Gpart[t2];
      if (v != 0.f) atomicAdd(&G[(t2 >> 8) * LINn + n0 + (t2 & 255)], v);
    }
  }
}

// S[b][n] += sum_{k in chunk} G[b][k]*Wf1[k][n]. grid (16,8), block 512.
__global__ void k_final1(const float* __restrict__ G, const float* __restrict__ Wf1,
                         float* __restrict__ S) {
  __shared__ float g[128];
  int b = blockIdx.x, kz = blockIdx.y, tid = threadIdx.x;
  if (tid < 128) g[tid] = G[b * 1024 + kz * 128 + tid];
  __syncthreads();
  float acc = 0.f;
  const float* W = Wf1 + (size_t)(kz * 128) * 512 + tid;
  for (int k = 0; k < 128; ++k) acc += g[k] * W[(size_t)k * 512];
  atomicAdd(&S[b * 512 + tid], acc);
}

// out[b] = relu(S[b]+bf1) @ Wf2 + bf2. grid 16, block 256.
__global__ void k_final2(const float* __restrict__ S, const float* __restrict__ bf1,
                         const float* __restrict__ Wf2, const float* __restrict__ bf2,
                         float* __restrict__ out) {
  __shared__ float mid[512];
  __shared__ float part[256];
  int b = blockIdx.x, tid = threadIdx.x;
  for (int t = tid; t < 512; t += 256) mid[t] = fmaxf(S[b * 512 + t] + bf1[t], 0.f);
  __syncthreads();
  int o = tid & 15, seg = tid >> 4;
  float s = 0.f;
#pragma unroll
  for (int t = 0; t < 32; ++t) {
    int j = seg * 32 + t;
    s += mid[j] * Wf2[j * 16 + o];
  }
  part[tid] = s;
  __syncthreads();
  if (tid < 16) {
    float v = bf2[tid];
#pragma unroll
    for (int sg = 0; sg < 16; ++sg) v += part[sg * 16 + tid];
    out[b * 16 + tid] = v;
  }
}

extern "C" void kernel_launch(void* const* d_in, const int* in_sizes, int n_in,
                              void* d_out, int out_size, void* d_ws, size_t ws_size,
                              hipStream_t stream) {
  const float* box_feats  = (const float*)d_in[2];
  const float* q_feats    = (const float*)d_in[3];
  const float* box_coords = (const float*)d_in[4];
  const int*   index      = (const int*)d_in[5];
  const float* W1  = (const float*)d_in[6];
  const float* b1  = (const float*)d_in[7];
  const float* W2  = (const float*)d_in[8];
  const float* b2  = (const float*)d_in[9];
  const float* W3  = (const float*)d_in[10];
  const float* b3  = (const float*)d_in[11];
  const float* Wf1 = (const float*)d_in[12];
  const float* bf1 = (const float*)d_in[13];
  const float* Wf2 = (const float*)d_in[14];
  const float* bf2 = (const float*)d_in[15];
  float* out = (float*)d_out;

  char* ws = (char*)d_ws;
  size_t off = 0;
  auto alloc = [&](size_t bytes) { void* p = ws + off; off += (bytes + 255) & ~(size_t)255; return p; };
  u16* W1abT = (u16*)alloc((size_t)2048 * 2048 * 2);
  u16* W2T   = (u16*)alloc((size_t)1024 * 1024 * 2);
  u16* W3T   = (u16*)alloc((size_t)1024 * 1024 * 2);
  u16* BFb   = (u16*)alloc((size_t)NBIn * Cn * 2);
  float* P12  = (float*)alloc((size_t)640 * 2048 * 4);
  float* Pc   = (float*)alloc((size_t)Bn * LINn * 4);
  float* dotC = (float*)alloc((size_t)NPAIRn * 4);
  float* iouC = (float*)alloc((size_t)NPAIRn * 4);
  float* oijC = (float*)alloc((size_t)NPAIRn * 4);
  float* ojiC = (float*)alloc((size_t)NPAIRn * 4);
  int* pairList = (int*)alloc((size_t)(NPAIRn + 256) * 4);
  int* batchC   = (int*)alloc((size_t)(NPAIRn + 256) * 4);
  int* cnt2     = (int*)alloc(64);
  float* G  = (float*)alloc((size_t)Bn * LINn * 4);
  float* S  = (float*)alloc((size_t)Bn * 512 * 4);
  u16* H1 = (u16*)alloc((size_t)(NPAIRn + 256) * 1024 * 2);
  u16* H2 = (u16*)alloc((size_t)(NPAIRn + 256) * 1024 * 2);

  k_transpose_all<<<dim3(32, 64, 4), 256, 0, stream>>>(W1, W2, W3, W1abT, W2T, W3T);
  k_f2b<<<(NBIn * Cn / 4 + 255) / 256, 256, 0, stream>>>((const float4*)box_feats,
                                                         (ushort4*)BFb, NBIn * Cn / 4);
  k_build<<<16, 256, 0, stream>>>(index, pairList, batchC, cnt2);
  hipMemsetAsync(G, 0, (size_t)Bn * LINn * 4, stream);
  hipMemsetAsync(S, 0, (size_t)Bn * 512 * 4, stream);
  k_pcinit<<<4, 256, 0, stream>>>(b1, Pc);
  k_pconst<<<dim3(4, 32), 256, 0, stream>>>(q_feats, W1, Pc);
  k_pairscalars<<<648, 256, 0, stream>>>(box_feats, box_coords, pairList, cnt2,
                                         dotC, iouC, oijC, ojiC);
  // P12 = rank-1 terms + Pc, then P-GEMM atomically accumulates BFb @ [W1a|W1b]
  k_pinit<<<NBIn, 256, 0, stream>>>(Pc, box_coords, W1, P12);
  k_gemmP<<<dim3(5, 32, 4), 256, 0, stream>>>(BFb, W1abT, 2048, 2048, 512, NBIn, P12);
  k_h1<<<2592, 256, 0, stream>>>(P12, dotC, iouC, oijC, ojiC, pairList, cnt2, W1, H1);
  // H2 = relu(H1 @ W2 + b2)   (256x256 tiles, 8-wave, XCD-affine remap)
  k_gemm2<1><<<dim3(324, 1, 1), 512, 0, stream>>>(H1, W2T, cnt2, H2, b2, nullptr, nullptr);
  // G[b] += relu(H2 @ W3 + b3)  (fused masked pair-reduction)
  k_gemm2<2><<<dim3(324, 1, 1), 512, 0, stream>>>(H2, W3T, cnt2, nullptr, b3, batchC, G);
  k_final1<<<dim3(16, 8), 512, 0, stream>>>(G, Wf1, S);
  k_final2<<<16, 256, 0, stream>>>(S, bf1, Wf2, bf2, out);
}

// Round 13
// 150.916 us; speedup vs baseline: 1.1401x; 1.1401x over previous
//
#include <hip/hip_runtime.h>
#include <stdint.h>

typedef unsigned short u16;
typedef __attribute__((ext_vector_type(8))) short short8;
typedef __attribute__((ext_vector_type(4))) float f32x4;

#define Bn 16
#define Kn 36
#define Cn 2048
#define Qn 1024
#define LINn 1024
#define NPp 1296      // 36*36 pairs per batch
#define NPAIRn 20736  // 16*1296
#define NBIn 576      // 16*36

__device__ __forceinline__ u16 f2bf(float f) {
  union { float f; unsigned int u; } v; v.f = f;
  unsigned int r = v.u + 0x7FFFu + ((v.u >> 16) & 1u);
  return (u16)(r >> 16);
}

__device__ __forceinline__ void llds16(const void* g, void* l) {
  __builtin_amdgcn_global_load_lds((const __attribute__((address_space(1))) void*)g,
                                   (__attribute__((address_space(3))) void*)l, 16, 0, 0);
}

// All four weight transposes in one launch. grid (32,64,4), block 256.
__global__ void k_transpose_all(const float* __restrict__ W1, const float* __restrict__ W2,
                                const float* __restrict__ W3, u16* __restrict__ W1abT,
                                u16* __restrict__ W2T, u16* __restrict__ W3T) {
  __shared__ float tile[32][33];
  int z = blockIdx.z;
  const float* src; u16* dst; int ld_dst;
  if (z == 0)      { if (blockIdx.y >= 32) return; src = W2; dst = W2T; ld_dst = 1024; }
  else if (z == 1) { if (blockIdx.y >= 32) return; src = W3; dst = W3T; ld_dst = 1024; }
  else if (z == 2) { src = W1; dst = W1abT; ld_dst = 2048; }
  else             { src = W1 + (size_t)2048 * 1024; dst = W1abT + (size_t)1024 * 2048; ld_dst = 2048; }
  int n0 = blockIdx.x * 32, k0 = blockIdx.y * 32;
  int tx = threadIdx.x & 31, ty = threadIdx.x >> 5;  // 32x8
#pragma unroll
  for (int r = 0; r < 32; r += 8)
    tile[ty + r][tx] = src[(size_t)(k0 + ty + r) * 1024 + (n0 + tx)];
  __syncthreads();
#pragma unroll
  for (int r = 0; r < 32; r += 8)
    dst[(size_t)(n0 + ty + r) * ld_dst + (k0 + tx)] = f2bf(tile[tx][ty + r]);
}

__global__ void k_f2b(const float4* __restrict__ src, ushort4* __restrict__ dst, int n4) {
  int i = blockIdx.x * 256 + threadIdx.x;
  if (i < n4) {
    float4 v = src[i];
    ushort4 o;
    o.x = f2bf(v.x); o.y = f2bf(v.y); o.z = f2bf(v.z); o.w = f2bf(v.w);
    dst[i] = o;
  }
}

// Build compacted valid-pair list; also zero-init G, S, Pc (replaces two
// memsets + k_pcinit -> 3 fewer launches). grid 16 (block per batch), 256 thr.
__global__ void k_build(const int* __restrict__ index, int* __restrict__ pairList,
                        int* __restrict__ batchC, int* __restrict__ cnt2,
                        float* __restrict__ G, float* __restrict__ S,
                        float* __restrict__ Pc) {
  __shared__ int offs[17];
  int tid = threadIdx.x;
  int b = blockIdx.x;
  if (tid == 0) {
    int o = 0;
    for (int i = 0; i < Bn; ++i) { offs[i] = o; int v = index[i]; o += v * v; }
    offs[16] = o;
    if (b == 0) {
      cnt2[0] = o;
      cnt2[1] = (o + 127) & ~127;
    }
  }
  // zero-init this batch's accumulators
  for (int t = tid; t < LINn; t += 256) { G[b * LINn + t] = 0.f; Pc[b * LINn + t] = 0.f; }
  for (int t = tid; t < 512; t += 256) S[b * 512 + t] = 0.f;
  __syncthreads();
  int v = index[b]; int n = v * v; int base = offs[b];
  for (int t = tid; t < n; t += 256) {
    int i = t / v, j = t - i * v;
    pairList[base + t] = b * NPp + i * Kn + j;
    batchC[base + t] = b;
  }
  if (b == 0) {
    int total = offs[16];
    int totalPad = (total + 255) & ~255;
    for (int t = total + tid; t < totalPad; t += 256) {
      pairList[t] = 0;
      batchC[t] = 0;
    }
  }
}

// Pc[b][n] += sum_k q[b][k]*Wq[k][n], Wq streamed once. grid (4 nblk, 32 kz), block 256.
__global__ void k_pconst(const float* __restrict__ q, const float* __restrict__ W1,
                         float* __restrict__ Pc) {
  __shared__ float qs[Bn][32];
  int n = blockIdx.x * 256 + threadIdx.x;
  int k0 = blockIdx.y * 32;
  const float* Wq = W1 + (size_t)(2 * Cn) * LINn;
  for (int t = threadIdx.x; t < Bn * 32; t += 256) {
    int b = t >> 5, k = t & 31;
    qs[b][k] = q[b * Qn + k0 + k];
  }
  __syncthreads();
  float acc[Bn];
#pragma unroll
  for (int b = 0; b < Bn; ++b) acc[b] = 0.f;
  for (int k = 0; k < 32; ++k) {
    float w = Wq[(size_t)(k0 + k) * LINn + n];
#pragma unroll
    for (int b = 0; b < Bn; ++b) acc[b] += qs[b][k] * w;
  }
#pragma unroll
  for (int b = 0; b < Bn; ++b) atomicAdd(&Pc[b * LINn + n], acc[b]);
}

// per-compacted-pair scalars. 1 wave per pair, 4 waves/block, grid-stride.
__global__ void k_pairscalars(const float* __restrict__ bfm, const float* __restrict__ bc,
                              const int* __restrict__ pairList, const int* __restrict__ cnt2,
                              float* __restrict__ dotC, float* __restrict__ iouC,
                              float* __restrict__ oijC, float* __restrict__ ojiC) {
  int cnt = cnt2[0];
  int lane = threadIdx.x & 63;
  for (int m = blockIdx.x * 4 + (threadIdx.x >> 6); m < cnt; m += gridDim.x * 4) {
    int p = pairList[m];
    int b = p / NPp, rem = p - b * NPp, i = rem / Kn, j = rem - (rem / Kn) * Kn;
    const float4* Ai = (const float4*)(bfm + (size_t)(b * Kn + i) * Cn);
    const float4* Aj = (const float4*)(bfm + (size_t)(b * Kn + j) * Cn);
    float s = 0.f;
#pragma unroll
    for (int t = 0; t < Cn / 4 / 64; ++t) {
      float4 x = Ai[lane + t * 64], y = Aj[lane + t * 64];
      s += x.x * y.x + x.y * y.y + x.z * y.z + x.w * y.w;
    }
#pragma unroll
    for (int o = 32; o > 0; o >>= 1) s += __shfl_down(s, o);
    if (lane == 0) {
      const float* ci = bc + (size_t)(b * Kn + i) * 6;
      const float* cj = bc + (size_t)(b * Kn + j) * 6;
      float ai = (ci[2] - ci[0]) * (ci[3] - ci[1]);
      float aj = (cj[2] - cj[0]) * (cj[3] - cj[1]);
      float lr = fmaxf(0.f, fminf(ci[2], cj[2]) - fmaxf(ci[0], cj[0]));
      float ud = fmaxf(0.f, fminf(ci[3], cj[3]) - fmaxf(ci[1], cj[1]));
      float ov = lr * ud;
      dotC[m] = s;
      iouC[m] = ov / (ai + aj - ov);
      oijC[m] = ov / ai;
      ojiC[m] = ov / aj;
    }
  }
}

// P12 init: P12[bi][c] = bc rank-1 terms + (c<1024 ? Pc[b][c] + b1[c] : 0).
__global__ void k_pinit(const float* __restrict__ Pc, const float* __restrict__ b1,
                        const float* __restrict__ bc, const float* __restrict__ W1,
                        float* __restrict__ P12) {
  int bi = blockIdx.x;
  int b = bi / Kn;
  const float* c = bc + (size_t)bi * 6;
  const float* W = W1 + (size_t)(2 * Cn + Qn + 1) * LINn;  // row 5121
#pragma unroll
  for (int it = 0; it < 8; ++it) {
    int cc = it * 256 + threadIdx.x;  // 0..2047
    int n = cc & 1023;
    int rbase = (cc < 1024) ? 0 : 6;
    float a = 0.f;
#pragma unroll
    for (int t = 0; t < 6; ++t) a += c[t] * W[(size_t)(rbase + t) * LINn + n];
    if (cc < 1024) a += Pc[b * LINn + n] + b1[n];
    P12[(size_t)bi * 2048 + cc] = a;
  }
}

// H1[m][n] = relu(P1'[b,i][n] + P2[b,j][n] + d*wd + u*wu + o1*wa + o2*wb) -> bf16
__global__ void k_h1(const float* __restrict__ P12,
                     const float* __restrict__ dotC, const float* __restrict__ iouC,
                     const float* __restrict__ oijC, const float* __restrict__ ojiC,
                     const int* __restrict__ pairList, const int* __restrict__ cnt2,
                     const float* __restrict__ W1, u16* __restrict__ H1) {
  int cnt = cnt2[0];
  int t = threadIdx.x;
  const float4* wd = (const float4*)(W1 + (size_t)(2 * Cn + Qn) * LINn);       // 5120
  const float4* wu = (const float4*)(W1 + (size_t)(2 * Cn + Qn + 13) * LINn);  // 5133
  const float4* wa = (const float4*)(W1 + (size_t)(2 * Cn + Qn + 14) * LINn);  // 5134
  const float4* wb = (const float4*)(W1 + (size_t)(2 * Cn + Qn + 15) * LINn);  // 5135
  float4 e1 = wd[t], e2 = wu[t], e3 = wa[t], e4 = wb[t];
  for (int m = blockIdx.x; m < cnt; m += gridDim.x) {
    int p = pairList[m];
    int b = p / NPp, rem = p - b * NPp, i = rem / Kn, j = rem - (rem / Kn) * Kn;
    float d = dotC[m], u = iouC[m], o1 = oijC[m], o2 = ojiC[m];
    const float4* p1 = (const float4*)(P12 + (size_t)(b * Kn + i) * 2048);
    const float4* p2 = (const float4*)(P12 + (size_t)(b * Kn + j) * 2048 + 1024);
    ushort4* outp = (ushort4*)(H1 + (size_t)m * 1024);
    float4 v1 = p1[t], v2 = p2[t];
    ushort4 o;
    o.x = f2bf(fmaxf(v1.x + v2.x + d * e1.x + u * e2.x + o1 * e3.x + o2 * e4.x, 0.f));
    o.y = f2bf(fmaxf(v1.y + v2.y + d * e1.y + u * e2.y + o1 * e3.y + o2 * e4.y, 0.f));
    o.z = f2bf(fmaxf(v1.z + v2.z + d * e1.z + u * e2.z + o1 * e3.z + o2 * e4.z, 0.f));
    o.w = f2bf(fmaxf(v1.w + v2.w + d * e1.w + u * e2.w + o1 * e3.w + o2 * e4.w, 0.f));
    outp[t] = o;
  }
}

// 128x64-tile bf16 MFMA GEMM, 2-buffer counted-vmcnt pipeline, BK=64, 48KB LDS
// (3 blocks/CU) — the R6/R11 proven configuration (44 us per big GEMM).
// EPI 0: split-K atomicAdd into pre-initialized Cf (3D grid).
// EPI 1/2: 1D grid, bijective XCD-affinity remap over active blocks.
template <int EPI>
__global__ void __launch_bounds__(256) k_gemm(
    const u16* __restrict__ A, const u16* __restrict__ BT,
    int N, int K, int KC, int Mvalid, const int* __restrict__ cnt2,
    float* __restrict__ Cf, u16* __restrict__ Cb,
    const float* __restrict__ bias,
    const int* __restrict__ batchC, float* __restrict__ G) {
  __shared__ u16 Alds[2][128 * 64];   // 2 x 16 KB
  __shared__ u16 Blds[2][64 * 64];    // 2 x 8 KB
  __shared__ float Gpart[(EPI == 2) ? (Bn * 64) : 4];

  const int tid = threadIdx.x;
  const int wave = tid >> 6, lane = tid & 63;
  const int wm = (wave >> 1) * 64, wn = (wave & 1) * 32;

  int Mv = Mvalid;
  int m0, n0;
  if (EPI == 0) {
    m0 = blockIdx.x * 128;
    n0 = blockIdx.y * 64;
  } else {
    Mv = cnt2[0];
    int nMt = (Mv + 127) >> 7;
    int nact = nMt * 16;                 // active blocks (16 N-tiles of 64)
    int id = blockIdx.x;
    if (id >= nact) return;
    int q = nact >> 3, r = nact & 7;
    int xcd = id & 7, rank = id >> 3;
    int wg = (xcd < r ? xcd * (q + 1) : r * (q + 1) + (xcd - r) * q) + rank;
    m0 = (wg >> 4) * 128;
    n0 = (wg & 15) * 64;
  }
  if (EPI == 2) {
    for (int t = tid; t < Bn * 64; t += 256) Gpart[t] = 0.f;
  }

  f32x4 zero = {0.f, 0.f, 0.f, 0.f};
  f32x4 acc[4][2];
#pragma unroll
  for (int x = 0; x < 4; ++x)
#pragma unroll
    for (int y = 0; y < 2; ++y) acc[x][y] = zero;

  const int srow = tid >> 3;                          // 0..31
  const int sslot = ((tid & 7) ^ (srow & 7)) * 16;
  const size_t ldb = (size_t)K * 2;

  auto stage = [&](int buf, int k0) {
    char* aB = (char*)Alds[buf] + wave * 1024;
    char* bB = (char*)Blds[buf] + wave * 1024;
#pragma unroll
    for (int c = 0; c < 4; ++c) {
      int rg = m0 + c * 32 + srow; if (rg >= Mv) rg = Mv - 1;
      llds16((const char*)A + (size_t)rg * ldb + (size_t)k0 * 2 + sslot, aB + c * 4096);
    }
#pragma unroll
    for (int c = 0; c < 2; ++c) {
      int rg = n0 + c * 32 + srow;
      llds16((const char*)BT + (size_t)rg * ldb + (size_t)k0 * 2 + sslot, bB + c * 4096);
    }
  };

  auto compute = [&](int buf) {
    const char* Ab = (const char*)Alds[buf];
    const char* Bb = (const char*)Blds[buf];
    short8 af[2][4], bfr[2][2];
#pragma unroll
    for (int kk = 0; kk < 2; ++kk) {
#pragma unroll
      for (int f = 0; f < 4; ++f) {
        int rA = wm + f * 16 + (lane & 15);
        int sl = ((kk * 4 + (lane >> 4)) ^ (rA & 7)) * 16;
        af[kk][f] = *(const short8*)(Ab + (size_t)rA * 128 + sl);
      }
#pragma unroll
      for (int f = 0; f < 2; ++f) {
        int rB = wn + f * 16 + (lane & 15);
        int sl = ((kk * 4 + (lane >> 4)) ^ (rB & 7)) * 16;
        bfr[kk][f] = *(const short8*)(Bb + (size_t)rB * 128 + sl);
      }
    }
#pragma unroll
    for (int kk = 0; kk < 2; ++kk)
#pragma unroll
      for (int x = 0; x < 4; ++x)
#pragma unroll
        for (int y = 0; y < 2; ++y)
          acc[x][y] = __builtin_amdgcn_mfma_f32_16x16x32_bf16(af[kk][x], bfr[kk][y],
                                                              acc[x][y], 0, 0, 0);
  };

  const int kbeg = blockIdx.z * KC;
  const int nt = KC >> 6;
  stage(0, kbeg);
  for (int t = 0; t < nt; ++t) {
    if (t + 1 < nt) {
      stage((t + 1) & 1, kbeg + (t + 1) * 64);
      asm volatile("s_waitcnt vmcnt(6)" ::: "memory");  // tile t landed; t+1 in flight
    } else {
      asm volatile("s_waitcnt vmcnt(0)" ::: "memory");
    }
    __builtin_amdgcn_s_barrier();   // all waves' tile-t loads landed
    compute(t & 1);
    __builtin_amdgcn_s_barrier();   // readers done before next stage overwrites
  }

  if (EPI == 0) {
#pragma unroll
    for (int x = 0; x < 4; ++x) {
      int rb = m0 + wm + x * 16 + (lane >> 4) * 4;
#pragma unroll
      for (int r = 0; r < 4; ++r) {
        int row = rb + r;
        if (row < Mv) {
#pragma unroll
          for (int y = 0; y < 2; ++y)
            atomicAdd(&Cf[(size_t)row * N + (n0 + wn + y * 16 + (lane & 15))],
                      acc[x][y][r]);
        }
      }
    }
  } else if (EPI == 1) {
#pragma unroll
    for (int x = 0; x < 4; ++x) {
      int rb = m0 + wm + x * 16 + (lane >> 4) * 4;
#pragma unroll
      for (int r = 0; r < 4; ++r) {
        int row = rb + r;
#pragma unroll
        for (int y = 0; y < 2; ++y) {
          int col = n0 + wn + y * 16 + (lane & 15);
          Cb[(size_t)row * N + col] = f2bf(fmaxf(acc[x][y][r] + bias[col], 0.f));
        }
      }
    }
  } else {
    const int cnt = Mv;
#pragma unroll
    for (int x = 0; x < 4; ++x) {
      int rb = m0 + wm + x * 16 + (lane >> 4) * 4;
      int b0 = batchC[rb], b1 = batchC[rb + 1], b2 = batchC[rb + 2], b3 = batchC[rb + 3];
      float mk0 = (rb     < cnt) ? 1.f : 0.f;
      float mk1 = (rb + 1 < cnt) ? 1.f : 0.f;
      float mk2 = (rb + 2 < cnt) ? 1.f : 0.f;
      float mk3 = (rb + 3 < cnt) ? 1.f : 0.f;
#pragma unroll
      for (int y = 0; y < 2; ++y) {
        int coll = wn + y * 16 + (lane & 15);
        float bs = bias[n0 + coll];
        float s0 = mk0 * fmaxf(acc[x][y][0] + bs, 0.f);
        float s1 = mk1 * fmaxf(acc[x][y][1] + bs, 0.f);
        float s2 = mk2 * fmaxf(acc[x][y][2] + bs, 0.f);
        float s3 = mk3 * fmaxf(acc[x][y][3] + bs, 0.f);
        if (b0 == b3) {
          atomicAdd(&Gpart[b0 * 64 + coll], s0 + s1 + s2 + s3);
        } else {
          atomicAdd(&Gpart[b0 * 64 + coll], s0);
          atomicAdd(&Gpart[b1 * 64 + coll], s1);
          atomicAdd(&Gpart[b2 * 64 + coll], s2);
          atomicAdd(&Gpart[b3 * 64 + coll], s3);
        }
      }
    }
    __syncthreads();
    for (int t2 = tid; t2 < Bn * 64; t2 += 256) {
      float v = Gpart[t2];
      if (v != 0.f) atomicAdd(&G[(t2 >> 6) * LINn + n0 + (t2 & 63)], v);
    }
  }
}

// S[b][n] += sum_{k in chunk} G[b][k]*Wf1[k][n]. grid (16,8), block 512.
__global__ void k_final1(const float* __restrict__ G, const float* __restrict__ Wf1,
                         float* __restrict__ S) {
  __shared__ float g[128];
  int b = blockIdx.x, kz = blockIdx.y, tid = threadIdx.x;
  if (tid < 128) g[tid] = G[b * 1024 + kz * 128 + tid];
  __syncthreads();
  float acc = 0.f;
  const float* W = Wf1 + (size_t)(kz * 128) * 512 + tid;
  for (int k = 0; k < 128; ++k) acc += g[k] * W[(size_t)k * 512];
  atomicAdd(&S[b * 512 + tid], acc);
}

// out[b] = relu(S[b]+bf1) @ Wf2 + bf2. grid 16, block 256.
__global__ void k_final2(const float* __restrict__ S, const float* __restrict__ bf1,
                         const float* __restrict__ Wf2, const float* __restrict__ bf2,
                         float* __restrict__ out) {
  __shared__ float mid[512];
  __shared__ float part[256];
  int b = blockIdx.x, tid = threadIdx.x;
  for (int t = tid; t < 512; t += 256) mid[t] = fmaxf(S[b * 512 + t] + bf1[t], 0.f);
  __syncthreads();
  int o = tid & 15, seg = tid >> 4;
  float s = 0.f;
#pragma unroll
  for (int t = 0; t < 32; ++t) {
    int j = seg * 32 + t;
    s += mid[j] * Wf2[j * 16 + o];
  }
  part[tid] = s;
  __syncthreads();
  if (tid < 16) {
    float v = bf2[tid];
#pragma unroll
    for (int sg = 0; sg < 16; ++sg) v += part[sg * 16 + tid];
    out[b * 16 + tid] = v;
  }
}

extern "C" void kernel_launch(void* const* d_in, const int* in_sizes, int n_in,
                              void* d_out, int out_size, void* d_ws, size_t ws_size,
                              hipStream_t stream) {
  const float* box_feats  = (const float*)d_in[2];
  const float* q_feats    = (const float*)d_in[3];
  const float* box_coords = (const float*)d_in[4];
  const int*   index      = (const int*)d_in[5];
  const float* W1  = (const float*)d_in[6];
  const float* b1  = (const float*)d_in[7];
  const float* W2  = (const float*)d_in[8];
  const float* b2  = (const float*)d_in[9];
  const float* W3  = (const float*)d_in[10];
  const float* b3  = (const float*)d_in[11];
  const float* Wf1 = (const float*)d_in[12];
  const float* bf1 = (const float*)d_in[13];
  const float* Wf2 = (const float*)d_in[14];
  const float* bf2 = (const float*)d_in[15];
  float* out = (float*)d_out;

  char* ws = (char*)d_ws;
  size_t off = 0;
  auto alloc = [&](size_t bytes) { void* p = ws + off; off += (bytes + 255) & ~(size_t)255; return p; };
  u16* W1abT = (u16*)alloc((size_t)2048 * 2048 * 2);
  u16* W2T   = (u16*)alloc((size_t)1024 * 1024 * 2);
  u16* W3T   = (u16*)alloc((size_t)1024 * 1024 * 2);
  u16* BFb   = (u16*)alloc((size_t)NBIn * Cn * 2);
  float* P12  = (float*)alloc((size_t)640 * 2048 * 4);
  float* Pc   = (float*)alloc((size_t)Bn * LINn * 4);
  float* dotC = (float*)alloc((size_t)NPAIRn * 4);
  float* iouC = (float*)alloc((size_t)NPAIRn * 4);
  float* oijC = (float*)alloc((size_t)NPAIRn * 4);
  float* ojiC = (float*)alloc((size_t)NPAIRn * 4);
  int* pairList = (int*)alloc((size_t)(NPAIRn + 256) * 4);
  int* batchC   = (int*)alloc((size_t)(NPAIRn + 256) * 4);
  int* cnt2     = (int*)alloc(64);
  float* G  = (float*)alloc((size_t)Bn * LINn * 4);
  float* S  = (float*)alloc((size_t)Bn * 512 * 4);
  u16* H1 = (u16*)alloc((size_t)NPAIRn * 1024 * 2);
  u16* H2 = (u16*)alloc((size_t)NPAIRn * 1024 * 2);

  k_transpose_all<<<dim3(32, 64, 4), 256, 0, stream>>>(W1, W2, W3, W1abT, W2T, W3T);
  k_f2b<<<(NBIn * Cn / 4 + 255) / 256, 256, 0, stream>>>((const float4*)box_feats,
                                                         (ushort4*)BFb, NBIn * Cn / 4);
  k_build<<<16, 256, 0, stream>>>(index, pairList, batchC, cnt2, G, S, Pc);
  k_pconst<<<dim3(4, 32), 256, 0, stream>>>(q_feats, W1, Pc);
  k_pairscalars<<<648, 256, 0, stream>>>(box_feats, box_coords, pairList, cnt2,
                                         dotC, iouC, oijC, ojiC);
  // P12 = rank-1 terms + Pc + b1, then P-GEMM atomically accumulates on top
  k_pinit<<<NBIn, 256, 0, stream>>>(Pc, b1, box_coords, W1, P12);
  k_gemm<0><<<dim3(5, 32, 4), 256, 0, stream>>>(BFb, W1abT, 2048, 2048, 512, NBIn, nullptr,
                                                P12, nullptr, nullptr, nullptr, nullptr);
  k_h1<<<2592, 256, 0, stream>>>(P12, dotC, iouC, oijC, ojiC, pairList, cnt2, W1, H1);
  // H2 = relu(H1 @ W2 + b2)   (1D grid, XCD-affine remap inside)
  k_gemm<1><<<dim3(2592, 1, 1), 256, 0, stream>>>(H1, W2T, 1024, 1024, 1024, 0, cnt2,
                                                  nullptr, H2, b2, nullptr, nullptr);
  // G[b] += relu(H2 @ W3 + b3)  (fused masked pair-reduction)
  k_gemm<2><<<dim3(2592, 1, 1), 256, 0, stream>>>(H2, W3T, 1024, 1024, 1024, 0, cnt2,
                                                  nullptr, nullptr, b3, batchC, G);
  k_final1<<<dim3(16, 8), 512, 0, stream>>>(G, Wf1, S);
  k_final2<<<16, 256, 0, stream>>>(S, bf1, Wf2, bf2, out);
}

// Round 14
// 143.177 us; speedup vs baseline: 1.2017x; 1.0540x over previous
//
#include <hip/hip_runtime.h>
#include <stdint.h>

typedef unsigned short u16;
typedef __attribute__((ext_vector_type(8))) short short8;
typedef __attribute__((ext_vector_type(4))) float f32x4;

#define Bn 16
#define Kn 36
#define Cn 2048
#define Qn 1024
#define LINn 1024
#define NPp 1296      // 36*36 pairs per batch
#define NPAIRn 20736  // 16*1296
#define NBIn 576      // 16*36

__device__ __forceinline__ u16 f2bf(float f) {
  union { float f; unsigned int u; } v; v.f = f;
  unsigned int r = v.u + 0x7FFFu + ((v.u >> 16) & 1u);
  return (u16)(r >> 16);
}

__device__ __forceinline__ void llds16(const void* g, void* l) {
  __builtin_amdgcn_global_load_lds((const __attribute__((address_space(1))) void*)g,
                                   (__attribute__((address_space(3))) void*)l, 16, 0, 0);
}

// Fused prep. grid (32,64,6), block 256.
// z=0..3: weight transposes (W2,W3 -> [n][k]; W1 halves -> W1abT).
// z=4:   box_feats f2b (flat block id over 294912 float4s) + zero G/S/Pc.
// z=5:   compacted pair-list build (blocks x<16, y==0; one batch per block).
__global__ void k_prep(const float* __restrict__ W1, const float* __restrict__ W2,
                       const float* __restrict__ W3, const float* __restrict__ box_feats,
                       const int* __restrict__ index,
                       u16* __restrict__ W1abT, u16* __restrict__ W2T,
                       u16* __restrict__ W3T, u16* __restrict__ BFb,
                       int* __restrict__ pairList, int* __restrict__ batchC,
                       int* __restrict__ cnt2, float* __restrict__ G,
                       float* __restrict__ S, float* __restrict__ Pc) {
  int z = blockIdx.z;
  int tid = threadIdx.x;
  if (z == 4) {
    int flat = blockIdx.y * 32 + blockIdx.x;   // 0..2047
    int i = flat * 256 + tid;
    const float4* src = (const float4*)box_feats;
    ushort4* dst = (ushort4*)BFb;
    if (i < NBIn * Cn / 4) {
      float4 v = src[i];
      ushort4 o;
      o.x = f2bf(v.x); o.y = f2bf(v.y); o.z = f2bf(v.z); o.w = f2bf(v.w);
      dst[i] = o;
    }
    if (flat < 5) {
      int id = flat * 256 + tid;               // stride 1280
      for (int t = id; t < Bn * LINn; t += 1280) { G[t] = 0.f; Pc[t] = 0.f; }
      for (int t = id; t < Bn * 512; t += 1280) S[t] = 0.f;
    }
    return;
  }
  if (z == 5) {
    if (blockIdx.y != 0 || blockIdx.x >= 16) return;
    __shared__ int offs[17];
    int b = blockIdx.x;
    if (tid == 0) {
      int o = 0;
      for (int i = 0; i < Bn; ++i) { offs[i] = o; int v = index[i]; o += v * v; }
      offs[16] = o;
      if (b == 0) {
        cnt2[0] = o;
        cnt2[1] = (o + 127) & ~127;
      }
    }
    __syncthreads();
    int v = index[b]; int n = v * v; int base = offs[b];
    for (int t = tid; t < n; t += 256) {
      int i = t / v, j = t - i * v;
      pairList[base + t] = b * NPp + i * Kn + j;
      batchC[base + t] = b;
    }
    if (b == 0) {
      int total = offs[16];
      int totalPad = (total + 255) & ~255;
      for (int t = total + tid; t < totalPad; t += 256) {
        pairList[t] = 0;
        batchC[t] = 0;
      }
    }
    return;
  }
  // z = 0..3: transposes
  __shared__ float tile[32][33];
  const float* src; u16* dst; int ld_dst;
  if (z == 0)      { if (blockIdx.y >= 32) return; src = W2; dst = W2T; ld_dst = 1024; }
  else if (z == 1) { if (blockIdx.y >= 32) return; src = W3; dst = W3T; ld_dst = 1024; }
  else if (z == 2) { src = W1; dst = W1abT; ld_dst = 2048; }
  else             { src = W1 + (size_t)2048 * 1024; dst = W1abT + (size_t)1024 * 2048; ld_dst = 2048; }
  int n0 = blockIdx.x * 32, k0 = blockIdx.y * 32;
  int tx = tid & 31, ty = tid >> 5;  // 32x8
#pragma unroll
  for (int r = 0; r < 32; r += 8)
    tile[ty + r][tx] = src[(size_t)(k0 + ty + r) * 1024 + (n0 + tx)];
  __syncthreads();
#pragma unroll
  for (int r = 0; r < 32; r += 8)
    dst[(size_t)(n0 + ty + r) * ld_dst + (k0 + tx)] = f2bf(tile[tx][ty + r]);
}

// Pc[b][n] += sum_k q[b][k]*Wq[k][n], Wq streamed once. grid (4 nblk, 32 kz), block 256.
__global__ void k_pconst(const float* __restrict__ q, const float* __restrict__ W1,
                         float* __restrict__ Pc) {
  __shared__ float qs[Bn][32];
  int n = blockIdx.x * 256 + threadIdx.x;
  int k0 = blockIdx.y * 32;
  const float* Wq = W1 + (size_t)(2 * Cn) * LINn;
  for (int t = threadIdx.x; t < Bn * 32; t += 256) {
    int b = t >> 5, k = t & 31;
    qs[b][k] = q[b * Qn + k0 + k];
  }
  __syncthreads();
  float acc[Bn];
#pragma unroll
  for (int b = 0; b < Bn; ++b) acc[b] = 0.f;
  for (int k = 0; k < 32; ++k) {
    float w = Wq[(size_t)(k0 + k) * LINn + n];
#pragma unroll
    for (int b = 0; b < Bn; ++b) acc[b] += qs[b][k] * w;
  }
#pragma unroll
  for (int b = 0; b < Bn; ++b) atomicAdd(&Pc[b * LINn + n], acc[b]);
}

// Fused mid-prep. grid 1224, block 256.
// id<648: per-pair scalars (1 wave/pair, grid-stride over 648*4 lanes-groups).
// id>=648: P12 init for row bi=id-648 (rank-1 terms + Pc + b1).
__global__ void k_mid(const float* __restrict__ bfm, const float* __restrict__ bc,
                      const int* __restrict__ pairList, const int* __restrict__ cnt2,
                      const float* __restrict__ Pc, const float* __restrict__ b1,
                      const float* __restrict__ W1,
                      float* __restrict__ dotC, float* __restrict__ iouC,
                      float* __restrict__ oijC, float* __restrict__ ojiC,
                      float* __restrict__ P12) {
  int id = blockIdx.x;
  if (id >= 648) {
    int bi = id - 648;             // 0..575
    int b = bi / Kn;
    const float* c = bc + (size_t)bi * 6;
    const float* W = W1 + (size_t)(2 * Cn + Qn + 1) * LINn;  // row 5121
#pragma unroll
    for (int it = 0; it < 8; ++it) {
      int cc = it * 256 + threadIdx.x;  // 0..2047
      int n = cc & 1023;
      int rbase = (cc < 1024) ? 0 : 6;
      float a = 0.f;
#pragma unroll
      for (int t = 0; t < 6; ++t) a += c[t] * W[(size_t)(rbase + t) * LINn + n];
      if (cc < 1024) a += Pc[b * LINn + n] + b1[n];
      P12[(size_t)bi * 2048 + cc] = a;
    }
    return;
  }
  int cnt = cnt2[0];
  int lane = threadIdx.x & 63;
  for (int m = id * 4 + (threadIdx.x >> 6); m < cnt; m += 648 * 4) {
    int p = pairList[m];
    int b = p / NPp, rem = p - b * NPp, i = rem / Kn, j = rem - (rem / Kn) * Kn;
    const float4* Ai = (const float4*)(bfm + (size_t)(b * Kn + i) * Cn);
    const float4* Aj = (const float4*)(bfm + (size_t)(b * Kn + j) * Cn);
    float s = 0.f;
#pragma unroll
    for (int t = 0; t < Cn / 4 / 64; ++t) {
      float4 x = Ai[lane + t * 64], y = Aj[lane + t * 64];
      s += x.x * y.x + x.y * y.y + x.z * y.z + x.w * y.w;
    }
#pragma unroll
    for (int o = 32; o > 0; o >>= 1) s += __shfl_down(s, o);
    if (lane == 0) {
      const float* ci = bc + (size_t)(b * Kn + i) * 6;
      const float* cj = bc + (size_t)(b * Kn + j) * 6;
      float ai = (ci[2] - ci[0]) * (ci[3] - ci[1]);
      float aj = (cj[2] - cj[0]) * (cj[3] - cj[1]);
      float lr = fmaxf(0.f, fminf(ci[2], cj[2]) - fmaxf(ci[0], cj[0]));
      float ud = fmaxf(0.f, fminf(ci[3], cj[3]) - fmaxf(ci[1], cj[1]));
      float ov = lr * ud;
      dotC[m] = s;
      iouC[m] = ov / (ai + aj - ov);
      oijC[m] = ov / ai;
      ojiC[m] = ov / aj;
    }
  }
}

// H1[m][n] = relu(P1'[b,i][n] + P2[b,j][n] + d*wd + u*wu + o1*wa + o2*wb) -> bf16
__global__ void k_h1(const float* __restrict__ P12,
                     const float* __restrict__ dotC, const float* __restrict__ iouC,
                     const float* __restrict__ oijC, const float* __restrict__ ojiC,
                     const int* __restrict__ pairList, const int* __restrict__ cnt2,
                     const float* __restrict__ W1, u16* __restrict__ H1) {
  int cnt = cnt2[0];
  int t = threadIdx.x;
  const float4* wd = (const float4*)(W1 + (size_t)(2 * Cn + Qn) * LINn);       // 5120
  const float4* wu = (const float4*)(W1 + (size_t)(2 * Cn + Qn + 13) * LINn);  // 5133
  const float4* wa = (const float4*)(W1 + (size_t)(2 * Cn + Qn + 14) * LINn);  // 5134
  const float4* wb = (const float4*)(W1 + (size_t)(2 * Cn + Qn + 15) * LINn);  // 5135
  float4 e1 = wd[t], e2 = wu[t], e3 = wa[t], e4 = wb[t];
  for (int m = blockIdx.x; m < cnt; m += gridDim.x) {
    int p = pairList[m];
    int b = p / NPp, rem = p - b * NPp, i = rem / Kn, j = rem - (rem / Kn) * Kn;
    float d = dotC[m], u = iouC[m], o1 = oijC[m], o2 = ojiC[m];
    const float4* p1 = (const float4*)(P12 + (size_t)(b * Kn + i) * 2048);
    const float4* p2 = (const float4*)(P12 + (size_t)(b * Kn + j) * 2048 + 1024);
    ushort4* outp = (ushort4*)(H1 + (size_t)m * 1024);
    float4 v1 = p1[t], v2 = p2[t];
    ushort4 o;
    o.x = f2bf(fmaxf(v1.x + v2.x + d * e1.x + u * e2.x + o1 * e3.x + o2 * e4.x, 0.f));
    o.y = f2bf(fmaxf(v1.y + v2.y + d * e1.y + u * e2.y + o1 * e3.y + o2 * e4.y, 0.f));
    o.z = f2bf(fmaxf(v1.z + v2.z + d * e1.z + u * e2.z + o1 * e3.z + o2 * e4.z, 0.f));
    o.w = f2bf(fmaxf(v1.w + v2.w + d * e1.w + u * e2.w + o1 * e3.w + o2 * e4.w, 0.f));
    outp[t] = o;
  }
}

// 128x64-tile bf16 MFMA GEMM, 2-buffer counted-vmcnt pipeline, BK=64, 48KB LDS
// (3 blocks/CU) — the R6/R11 proven configuration (44 us per big GEMM).
// EPI 0: split-K atomicAdd into pre-initialized Cf (3D grid).
// EPI 1/2: 1D grid, bijective XCD-affinity remap over active blocks.
template <int EPI>
__global__ void __launch_bounds__(256) k_gemm(
    const u16* __restrict__ A, const u16* __restrict__ BT,
    int N, int K, int KC, int Mvalid, const int* __restrict__ cnt2,
    float* __restrict__ Cf, u16* __restrict__ Cb,
    const float* __restrict__ bias,
    const int* __restrict__ batchC, float* __restrict__ G) {
  __shared__ u16 Alds[2][128 * 64];   // 2 x 16 KB
  __shared__ u16 Blds[2][64 * 64];    // 2 x 8 KB
  __shared__ float Gpart[(EPI == 2) ? (Bn * 64) : 4];

  const int tid = threadIdx.x;
  const int wave = tid >> 6, lane = tid & 63;
  const int wm = (wave >> 1) * 64, wn = (wave & 1) * 32;

  int Mv = Mvalid;
  int m0, n0;
  if (EPI == 0) {
    m0 = blockIdx.x * 128;
    n0 = blockIdx.y * 64;
  } else {
    Mv = cnt2[0];
    int nMt = (Mv + 127) >> 7;
    int nact = nMt * 16;                 // active blocks (16 N-tiles of 64)
    int id = blockIdx.x;
    if (id >= nact) return;
    int q = nact >> 3, r = nact & 7;
    int xcd = id & 7, rank = id >> 3;
    int wg = (xcd < r ? xcd * (q + 1) : r * (q + 1) + (xcd - r) * q) + rank;
    m0 = (wg >> 4) * 128;
    n0 = (wg & 15) * 64;
  }
  if (EPI == 2) {
    for (int t = tid; t < Bn * 64; t += 256) Gpart[t] = 0.f;
  }

  f32x4 zero = {0.f, 0.f, 0.f, 0.f};
  f32x4 acc[4][2];
#pragma unroll
  for (int x = 0; x < 4; ++x)
#pragma unroll
    for (int y = 0; y < 2; ++y) acc[x][y] = zero;

  const int srow = tid >> 3;                          // 0..31
  const int sslot = ((tid & 7) ^ (srow & 7)) * 16;
  const size_t ldb = (size_t)K * 2;

  auto stage = [&](int buf, int k0) {
    char* aB = (char*)Alds[buf] + wave * 1024;
    char* bB = (char*)Blds[buf] + wave * 1024;
#pragma unroll
    for (int c = 0; c < 4; ++c) {
      int rg = m0 + c * 32 + srow; if (rg >= Mv) rg = Mv - 1;
      llds16((const char*)A + (size_t)rg * ldb + (size_t)k0 * 2 + sslot, aB + c * 4096);
    }
#pragma unroll
    for (int c = 0; c < 2; ++c) {
      int rg = n0 + c * 32 + srow;
      llds16((const char*)BT + (size_t)rg * ldb + (size_t)k0 * 2 + sslot, bB + c * 4096);
    }
  };

  auto compute = [&](int buf) {
    const char* Ab = (const char*)Alds[buf];
    const char* Bb = (const char*)Blds[buf];
    short8 af[2][4], bfr[2][2];
#pragma unroll
    for (int kk = 0; kk < 2; ++kk) {
#pragma unroll
      for (int f = 0; f < 4; ++f) {
        int rA = wm + f * 16 + (lane & 15);
        int sl = ((kk * 4 + (lane >> 4)) ^ (rA & 7)) * 16;
        af[kk][f] = *(const short8*)(Ab + (size_t)rA * 128 + sl);
      }
#pragma unroll
      for (int f = 0; f < 2; ++f) {
        int rB = wn + f * 16 + (lane & 15);
        int sl = ((kk * 4 + (lane >> 4)) ^ (rB & 7)) * 16;
        bfr[kk][f] = *(const short8*)(Bb + (size_t)rB * 128 + sl);
      }
    }
#pragma unroll
    for (int kk = 0; kk < 2; ++kk)
#pragma unroll
      for (int x = 0; x < 4; ++x)
#pragma unroll
        for (int y = 0; y < 2; ++y)
          acc[x][y] = __builtin_amdgcn_mfma_f32_16x16x32_bf16(af[kk][x], bfr[kk][y],
                                                              acc[x][y], 0, 0, 0);
  };

  const int kbeg = blockIdx.z * KC;
  const int nt = KC >> 6;
  stage(0, kbeg);
  for (int t = 0; t < nt; ++t) {
    if (t + 1 < nt) {
      stage((t + 1) & 1, kbeg + (t + 1) * 64);
      asm volatile("s_waitcnt vmcnt(6)" ::: "memory");  // tile t landed; t+1 in flight
    } else {
      asm volatile("s_waitcnt vmcnt(0)" ::: "memory");
    }
    __builtin_amdgcn_s_barrier();   // all waves' tile-t loads landed
    compute(t & 1);
    __builtin_amdgcn_s_barrier();   // readers done before next stage overwrites
  }

  if (EPI == 0) {
#pragma unroll
    for (int x = 0; x < 4; ++x) {
      int rb = m0 + wm + x * 16 + (lane >> 4) * 4;
#pragma unroll
      for (int r = 0; r < 4; ++r) {
        int row = rb + r;
        if (row < Mv) {
#pragma unroll
          for (int y = 0; y < 2; ++y)
            atomicAdd(&Cf[(size_t)row * N + (n0 + wn + y * 16 + (lane & 15))],
                      acc[x][y][r]);
        }
      }
    }
  } else if (EPI == 1) {
#pragma unroll
    for (int x = 0; x < 4; ++x) {
      int rb = m0 + wm + x * 16 + (lane >> 4) * 4;
#pragma unroll
      for (int r = 0; r < 4; ++r) {
        int row = rb + r;
#pragma unroll
        for (int y = 0; y < 2; ++y) {
          int col = n0 + wn + y * 16 + (lane & 15);
          Cb[(size_t)row * N + col] = f2bf(fmaxf(acc[x][y][r] + bias[col], 0.f));
        }
      }
    }
  } else {
    const int cnt = Mv;
#pragma unroll
    for (int x = 0; x < 4; ++x) {
      int rb = m0 + wm + x * 16 + (lane >> 4) * 4;
      int b0 = batchC[rb], b1 = batchC[rb + 1], b2 = batchC[rb + 2], b3 = batchC[rb + 3];
      float mk0 = (rb     < cnt) ? 1.f : 0.f;
      float mk1 = (rb + 1 < cnt) ? 1.f : 0.f;
      float mk2 = (rb + 2 < cnt) ? 1.f : 0.f;
      float mk3 = (rb + 3 < cnt) ? 1.f : 0.f;
#pragma unroll
      for (int y = 0; y < 2; ++y) {
        int coll = wn + y * 16 + (lane & 15);
        float bs = bias[n0 + coll];
        float s0 = mk0 * fmaxf(acc[x][y][0] + bs, 0.f);
        float s1 = mk1 * fmaxf(acc[x][y][1] + bs, 0.f);
        float s2 = mk2 * fmaxf(acc[x][y][2] + bs, 0.f);
        float s3 = mk3 * fmaxf(acc[x][y][3] + bs, 0.f);
        if (b0 == b3) {
          atomicAdd(&Gpart[b0 * 64 + coll], s0 + s1 + s2 + s3);
        } else {
          atomicAdd(&Gpart[b0 * 64 + coll], s0);
          atomicAdd(&Gpart[b1 * 64 + coll], s1);
          atomicAdd(&Gpart[b2 * 64 + coll], s2);
          atomicAdd(&Gpart[b3 * 64 + coll], s3);
        }
      }
    }
    __syncthreads();
    for (int t2 = tid; t2 < Bn * 64; t2 += 256) {
      float v = Gpart[t2];
      if (v != 0.f) atomicAdd(&G[(t2 >> 6) * LINn + n0 + (t2 & 63)], v);
    }
  }
}

// S[b][n] += sum_{k in chunk} G[b][k]*Wf1[k][n]. grid (16,8), block 512.
__global__ void k_final1(const float* __restrict__ G, const float* __restrict__ Wf1,
                         float* __restrict__ S) {
  __shared__ float g[128];
  int b = blockIdx.x, kz = blockIdx.y, tid = threadIdx.x;
  if (tid < 128) g[tid] = G[b * 1024 + kz * 128 + tid];
  __syncthreads();
  float acc = 0.f;
  const float* W = Wf1 + (size_t)(kz * 128) * 512 + tid;
  for (int k = 0; k < 128; ++k) acc += g[k] * W[(size_t)k * 512];
  atomicAdd(&S[b * 512 + tid], acc);
}

// out[b] = relu(S[b]+bf1) @ Wf2 + bf2. grid 16, block 256.
__global__ void k_final2(const float* __restrict__ S, const float* __restrict__ bf1,
                         const float* __restrict__ Wf2, const float* __restrict__ bf2,
                         float* __restrict__ out) {
  __shared__ float mid[512];
  __shared__ float part[256];
  int b = blockIdx.x, tid = threadIdx.x;
  for (int t = tid; t < 512; t += 256) mid[t] = fmaxf(S[b * 512 + t] + bf1[t], 0.f);
  __syncthreads();
  int o = tid & 15, seg = tid >> 4;
  float s = 0.f;
#pragma unroll
  for (int t = 0; t < 32; ++t) {
    int j = seg * 32 + t;
    s += mid[j] * Wf2[j * 16 + o];
  }
  part[tid] = s;
  __syncthreads();
  if (tid < 16) {
    float v = bf2[tid];
#pragma unroll
    for (int sg = 0; sg < 16; ++sg) v += part[sg * 16 + tid];
    out[b * 16 + tid] = v;
  }
}

extern "C" void kernel_launch(void* const* d_in, const int* in_sizes, int n_in,
                              void* d_out, int out_size, void* d_ws, size_t ws_size,
                              hipStream_t stream) {
  const float* box_feats  = (const float*)d_in[2];
  const float* q_feats    = (const float*)d_in[3];
  const float* box_coords = (const float*)d_in[4];
  const int*   index      = (const int*)d_in[5];
  const float* W1  = (const float*)d_in[6];
  const float* b1  = (const float*)d_in[7];
  const float* W2  = (const float*)d_in[8];
  const float* b2  = (const float*)d_in[9];
  const float* W3  = (const float*)d_in[10];
  const float* b3  = (const float*)d_in[11];
  const float* Wf1 = (const float*)d_in[12];
  const float* bf1 = (const float*)d_in[13];
  const float* Wf2 = (const float*)d_in[14];
  const float* bf2 = (const float*)d_in[15];
  float* out = (float*)d_out;

  char* ws = (char*)d_ws;
  size_t off = 0;
  auto alloc = [&](size_t bytes) { void* p = ws + off; off += (bytes + 255) & ~(size_t)255; return p; };
  u16* W1abT = (u16*)alloc((size_t)2048 * 2048 * 2);
  u16* W2T   = (u16*)alloc((size_t)1024 * 1024 * 2);
  u16* W3T   = (u16*)alloc((size_t)1024 * 1024 * 2);
  u16* BFb   = (u16*)alloc((size_t)NBIn * Cn * 2);
  float* P12  = (float*)alloc((size_t)640 * 2048 * 4);
  float* Pc   = (float*)alloc((size_t)Bn * LINn * 4);
  float* dotC = (float*)alloc((size_t)NPAIRn * 4);
  float* iouC = (float*)alloc((size_t)NPAIRn * 4);
  float* oijC = (float*)alloc((size_t)NPAIRn * 4);
  float* ojiC = (float*)alloc((size_t)NPAIRn * 4);
  int* pairList = (int*)alloc((size_t)(NPAIRn + 256) * 4);
  int* batchC   = (int*)alloc((size_t)(NPAIRn + 256) * 4);
  int* cnt2     = (int*)alloc(64);
  float* G  = (float*)alloc((size_t)Bn * LINn * 4);
  float* S  = (float*)alloc((size_t)Bn * 512 * 4);
  u16* H1 = (u16*)alloc((size_t)NPAIRn * 1024 * 2);
  u16* H2 = (u16*)alloc((size_t)NPAIRn * 1024 * 2);

  // Fused prep: transposes + f2b + zero-init + pair-list build
  k_prep<<<dim3(32, 64, 6), 256, 0, stream>>>(W1, W2, W3, box_feats, index,
                                              W1abT, W2T, W3T, BFb,
                                              pairList, batchC, cnt2, G, S, Pc);
  k_pconst<<<dim3(4, 32), 256, 0, stream>>>(q_feats, W1, Pc);
  // Fused mid: pair scalars (blocks 0..647) + P12 init (blocks 648..1223)
  k_mid<<<1224, 256, 0, stream>>>(box_feats, box_coords, pairList, cnt2, Pc, b1, W1,
                                  dotC, iouC, oijC, ojiC, P12);
  // P-GEMM atomically accumulates BFb @ [W1a|W1b] onto the initialized P12
  k_gemm<0><<<dim3(5, 32, 4), 256, 0, stream>>>(BFb, W1abT, 2048, 2048, 512, NBIn, nullptr,
                                                P12, nullptr, nullptr, nullptr, nullptr);
  k_h1<<<2592, 256, 0, stream>>>(P12, dotC, iouC, oijC, ojiC, pairList, cnt2, W1, H1);
  // H2 = relu(H1 @ W2 + b2)   (1D grid, XCD-affine remap inside)
  k_gemm<1><<<dim3(2592, 1, 1), 256, 0, stream>>>(H1, W2T, 1024, 1024, 1024, 0, cnt2,
                                                  nullptr, H2, b2, nullptr, nullptr);
  // G[b] += relu(H2 @ W3 + b3)  (fused masked pair-reduction)
  k_gemm<2><<<dim3(2592, 1, 1), 256, 0, stream>>>(H2, W3T, 1024, 1024, 1024, 0, cnt2,
                                                  nullptr, nullptr, b3, batchC, G);
  k_final1<<<dim3(16, 8), 512, 0, stream>>>(G, Wf1, S);
  k_final2<<<16, 256, 0, stream>>>(S, bf1, Wf2, bf2, out);
}

// Round 15
// 141.715 us; speedup vs baseline: 1.2141x; 1.0103x over previous
//
#include <hip/hip_runtime.h>
#include <stdint.h>

typedef unsigned short u16;
typedef __attribute__((ext_vector_type(8))) short short8;
typedef __attribute__((ext_vector_type(4))) float f32x4;

#define Bn 16
#define Kn 36
#define Cn 2048
#define Qn 1024
#define LINn 1024
#define NPp 1296      // 36*36 pairs per batch
#define NPAIRn 20736  // 16*1296
#define NBIn 576      // 16*36

__device__ __forceinline__ u16 f2bf(float f) {
  union { float f; unsigned int u; } v; v.f = f;
  unsigned int r = v.u + 0x7FFFu + ((v.u >> 16) & 1u);
  return (u16)(r >> 16);
}

__device__ __forceinline__ void llds16(const void* g, void* l) {
  __builtin_amdgcn_global_load_lds((const __attribute__((address_space(1))) void*)g,
                                   (__attribute__((address_space(3))) void*)l, 16, 0, 0);
}

// Fused prep. grid (32,64,6), block 256.
// z=0..3: weight transposes (W2,W3 -> [n][k]; W1 halves -> W1abT).
// z=4:   box_feats f2b (flat block id over 294912 float4s) + zero G/S/Pc.
// z=5:   compacted pair-list build (blocks x<16, y==0; one batch per block).
__global__ void k_prep(const float* __restrict__ W1, const float* __restrict__ W2,
                       const float* __restrict__ W3, const float* __restrict__ box_feats,
                       const int* __restrict__ index,
                       u16* __restrict__ W1abT, u16* __restrict__ W2T,
                       u16* __restrict__ W3T, u16* __restrict__ BFb,
                       int* __restrict__ pairList, int* __restrict__ batchC,
                       int* __restrict__ cnt2, float* __restrict__ G,
                       float* __restrict__ S, float* __restrict__ Pc) {
  int z = blockIdx.z;
  int tid = threadIdx.x;
  if (z == 4) {
    int flat = blockIdx.y * 32 + blockIdx.x;   // 0..2047
    int i = flat * 256 + tid;
    const float4* src = (const float4*)box_feats;
    ushort4* dst = (ushort4*)BFb;
    if (i < NBIn * Cn / 4) {
      float4 v = src[i];
      ushort4 o;
      o.x = f2bf(v.x); o.y = f2bf(v.y); o.z = f2bf(v.z); o.w = f2bf(v.w);
      dst[i] = o;
    }
    if (flat < 5) {
      int id = flat * 256 + tid;               // stride 1280
      for (int t = id; t < Bn * LINn; t += 1280) { G[t] = 0.f; Pc[t] = 0.f; }
      for (int t = id; t < Bn * 512; t += 1280) S[t] = 0.f;
    }
    return;
  }
  if (z == 5) {
    if (blockIdx.y != 0 || blockIdx.x >= 16) return;
    __shared__ int offs[17];
    int b = blockIdx.x;
    if (tid == 0) {
      int o = 0;
      for (int i = 0; i < Bn; ++i) { offs[i] = o; int v = index[i]; o += v * v; }
      offs[16] = o;
      if (b == 0) {
        cnt2[0] = o;
        cnt2[1] = (o + 127) & ~127;
      }
    }
    __syncthreads();
    int v = index[b]; int n = v * v; int base = offs[b];
    for (int t = tid; t < n; t += 256) {
      int i = t / v, j = t - i * v;
      pairList[base + t] = b * NPp + i * Kn + j;
      batchC[base + t] = b;
    }
    if (b == 0) {
      int total = offs[16];
      int totalPad = (total + 255) & ~255;
      for (int t = total + tid; t < totalPad; t += 256) {
        pairList[t] = 0;
        batchC[t] = 0;
      }
    }
    return;
  }
  // z = 0..3: transposes
  __shared__ float tile[32][33];
  const float* src; u16* dst; int ld_dst;
  if (z == 0)      { if (blockIdx.y >= 32) return; src = W2; dst = W2T; ld_dst = 1024; }
  else if (z == 1) { if (blockIdx.y >= 32) return; src = W3; dst = W3T; ld_dst = 1024; }
  else if (z == 2) { src = W1; dst = W1abT; ld_dst = 2048; }
  else             { src = W1 + (size_t)2048 * 1024; dst = W1abT + (size_t)1024 * 2048; ld_dst = 2048; }
  int n0 = blockIdx.x * 32, k0 = blockIdx.y * 32;
  int tx = tid & 31, ty = tid >> 5;  // 32x8
#pragma unroll
  for (int r = 0; r < 32; r += 8)
    tile[ty + r][tx] = src[(size_t)(k0 + ty + r) * 1024 + (n0 + tx)];
  __syncthreads();
#pragma unroll
  for (int r = 0; r < 32; r += 8)
    dst[(size_t)(n0 + ty + r) * ld_dst + (k0 + tx)] = f2bf(tile[tx][ty + r]);
}

// Pc[b][n] += sum_k q[b][k]*Wq[k][n], Wq streamed once. grid (4 nblk, 32 kz), block 256.
__global__ void k_pconst(const float* __restrict__ q, const float* __restrict__ W1,
                         float* __restrict__ Pc) {
  __shared__ float qs[Bn][32];
  int n = blockIdx.x * 256 + threadIdx.x;
  int k0 = blockIdx.y * 32;
  const float* Wq = W1 + (size_t)(2 * Cn) * LINn;
  for (int t = threadIdx.x; t < Bn * 32; t += 256) {
    int b = t >> 5, k = t & 31;
    qs[b][k] = q[b * Qn + k0 + k];
  }
  __syncthreads();
  float acc[Bn];
#pragma unroll
  for (int b = 0; b < Bn; ++b) acc[b] = 0.f;
  for (int k = 0; k < 32; ++k) {
    float w = Wq[(size_t)(k0 + k) * LINn + n];
#pragma unroll
    for (int b = 0; b < Bn; ++b) acc[b] += qs[b][k] * w;
  }
#pragma unroll
  for (int b = 0; b < Bn; ++b) atomicAdd(&Pc[b * LINn + n], acc[b]);
}

// Fused mid-prep. grid 1224, block 256.
// id<648: per-pair scalars (1 wave/pair, grid-stride).
// id>=648: P12 init for row bi=id-648 (rank-1 terms + Pc + b1).
__global__ void k_mid(const float* __restrict__ bfm, const float* __restrict__ bc,
                      const int* __restrict__ pairList, const int* __restrict__ cnt2,
                      const float* __restrict__ Pc, const float* __restrict__ b1,
                      const float* __restrict__ W1,
                      float* __restrict__ dotC, float* __restrict__ iouC,
                      float* __restrict__ oijC, float* __restrict__ ojiC,
                      float* __restrict__ P12) {
  int id = blockIdx.x;
  if (id >= 648) {
    int bi = id - 648;             // 0..575
    int b = bi / Kn;
    const float* c = bc + (size_t)bi * 6;
    const float* W = W1 + (size_t)(2 * Cn + Qn + 1) * LINn;  // row 5121
#pragma unroll
    for (int it = 0; it < 8; ++it) {
      int cc = it * 256 + threadIdx.x;  // 0..2047
      int n = cc & 1023;
      int rbase = (cc < 1024) ? 0 : 6;
      float a = 0.f;
#pragma unroll
      for (int t = 0; t < 6; ++t) a += c[t] * W[(size_t)(rbase + t) * LINn + n];
      if (cc < 1024) a += Pc[b * LINn + n] + b1[n];
      P12[(size_t)bi * 2048 + cc] = a;
    }
    return;
  }
  int cnt = cnt2[0];
  int lane = threadIdx.x & 63;
  for (int m = id * 4 + (threadIdx.x >> 6); m < cnt; m += 648 * 4) {
    int p = pairList[m];
    int b = p / NPp, rem = p - b * NPp, i = rem / Kn, j = rem - (rem / Kn) * Kn;
    const float4* Ai = (const float4*)(bfm + (size_t)(b * Kn + i) * Cn);
    const float4* Aj = (const float4*)(bfm + (size_t)(b * Kn + j) * Cn);
    float s = 0.f;
#pragma unroll
    for (int t = 0; t < Cn / 4 / 64; ++t) {
      float4 x = Ai[lane + t * 64], y = Aj[lane + t * 64];
      s += x.x * y.x + x.y * y.y + x.z * y.z + x.w * y.w;
    }
#pragma unroll
    for (int o = 32; o > 0; o >>= 1) s += __shfl_down(s, o);
    if (lane == 0) {
      const float* ci = bc + (size_t)(b * Kn + i) * 6;
      const float* cj = bc + (size_t)(b * Kn + j) * 6;
      float ai = (ci[2] - ci[0]) * (ci[3] - ci[1]);
      float aj = (cj[2] - cj[0]) * (cj[3] - cj[1]);
      float lr = fmaxf(0.f, fminf(ci[2], cj[2]) - fmaxf(ci[0], cj[0]));
      float ud = fmaxf(0.f, fminf(ci[3], cj[3]) - fmaxf(ci[1], cj[1]));
      float ov = lr * ud;
      dotC[m] = s;
      iouC[m] = ov / (ai + aj - ov);
      oijC[m] = ov / ai;
      ojiC[m] = ov / aj;
    }
  }
}

// H1[m][n] = relu(P1'[b,i][n] + P2[b,j][n] + d*wd + u*wu + o1*wa + o2*wb) -> bf16
__global__ void k_h1(const float* __restrict__ P12,
                     const float* __restrict__ dotC, const float* __restrict__ iouC,
                     const float* __restrict__ oijC, const float* __restrict__ ojiC,
                     const int* __restrict__ pairList, const int* __restrict__ cnt2,
                     const float* __restrict__ W1, u16* __restrict__ H1) {
  int cnt = cnt2[0];
  int t = threadIdx.x;
  const float4* wd = (const float4*)(W1 + (size_t)(2 * Cn + Qn) * LINn);       // 5120
  const float4* wu = (const float4*)(W1 + (size_t)(2 * Cn + Qn + 13) * LINn);  // 5133
  const float4* wa = (const float4*)(W1 + (size_t)(2 * Cn + Qn + 14) * LINn);  // 5134
  const float4* wb = (const float4*)(W1 + (size_t)(2 * Cn + Qn + 15) * LINn);  // 5135
  float4 e1 = wd[t], e2 = wu[t], e3 = wa[t], e4 = wb[t];
  for (int m = blockIdx.x; m < cnt; m += gridDim.x) {
    int p = pairList[m];
    int b = p / NPp, rem = p - b * NPp, i = rem / Kn, j = rem - (rem / Kn) * Kn;
    float d = dotC[m], u = iouC[m], o1 = oijC[m], o2 = ojiC[m];
    const float4* p1 = (const float4*)(P12 + (size_t)(b * Kn + i) * 2048);
    const float4* p2 = (const float4*)(P12 + (size_t)(b * Kn + j) * 2048 + 1024);
    ushort4* outp = (ushort4*)(H1 + (size_t)m * 1024);
    float4 v1 = p1[t], v2 = p2[t];
    ushort4 o;
    o.x = f2bf(fmaxf(v1.x + v2.x + d * e1.x + u * e2.x + o1 * e3.x + o2 * e4.x, 0.f));
    o.y = f2bf(fmaxf(v1.y + v2.y + d * e1.y + u * e2.y + o1 * e3.y + o2 * e4.y, 0.f));
    o.z = f2bf(fmaxf(v1.z + v2.z + d * e1.z + u * e2.z + o1 * e3.z + o2 * e4.z, 0.f));
    o.w = f2bf(fmaxf(v1.w + v2.w + d * e1.w + u * e2.w + o1 * e3.w + o2 * e4.w, 0.f));
    outp[t] = o;
  }
}

// 128x64-tile bf16 MFMA GEMM, 2-buffer counted-vmcnt pipeline, BK=64, 48KB LDS
// (3 blocks/CU) — the R6/R11 proven configuration (44 us per big GEMM).
// EPI 0: split-K atomicAdd into pre-initialized Cf (3D grid).
// EPI 1/2: 1D grid, bijective XCD-affinity remap over active blocks.
template <int EPI>
__global__ void __launch_bounds__(256) k_gemm(
    const u16* __restrict__ A, const u16* __restrict__ BT,
    int N, int K, int KC, int Mvalid, const int* __restrict__ cnt2,
    float* __restrict__ Cf, u16* __restrict__ Cb,
    const float* __restrict__ bias,
    const int* __restrict__ batchC, float* __restrict__ G) {
  __shared__ u16 Alds[2][128 * 64];   // 2 x 16 KB
  __shared__ u16 Blds[2][64 * 64];    // 2 x 8 KB
  __shared__ float Gpart[(EPI == 2) ? (Bn * 64) : 4];

  const int tid = threadIdx.x;
  const int wave = tid >> 6, lane = tid & 63;
  const int wm = (wave >> 1) * 64, wn = (wave & 1) * 32;

  int Mv = Mvalid;
  int m0, n0;
  if (EPI == 0) {
    m0 = blockIdx.x * 128;
    n0 = blockIdx.y * 64;
  } else {
    Mv = cnt2[0];
    int nMt = (Mv + 127) >> 7;
    int nact = nMt * 16;                 // active blocks (16 N-tiles of 64)
    int id = blockIdx.x;
    if (id >= nact) return;
    int q = nact >> 3, r = nact & 7;
    int xcd = id & 7, rank = id >> 3;
    int wg = (xcd < r ? xcd * (q + 1) : r * (q + 1) + (xcd - r) * q) + rank;
    m0 = (wg >> 4) * 128;
    n0 = (wg & 15) * 64;
  }
  if (EPI == 2) {
    for (int t = tid; t < Bn * 64; t += 256) Gpart[t] = 0.f;
  }

  f32x4 zero = {0.f, 0.f, 0.f, 0.f};
  f32x4 acc[4][2];
#pragma unroll
  for (int x = 0; x < 4; ++x)
#pragma unroll
    for (int y = 0; y < 2; ++y) acc[x][y] = zero;

  const int srow = tid >> 3;                          // 0..31
  const int sslot = ((tid & 7) ^ (srow & 7)) * 16;
  const size_t ldb = (size_t)K * 2;

  auto stage = [&](int buf, int k0) {
    char* aB = (char*)Alds[buf] + wave * 1024;
    char* bB = (char*)Blds[buf] + wave * 1024;
#pragma unroll
    for (int c = 0; c < 4; ++c) {
      int rg = m0 + c * 32 + srow; if (rg >= Mv) rg = Mv - 1;
      llds16((const char*)A + (size_t)rg * ldb + (size_t)k0 * 2 + sslot, aB + c * 4096);
    }
#pragma unroll
    for (int c = 0; c < 2; ++c) {
      int rg = n0 + c * 32 + srow;
      llds16((const char*)BT + (size_t)rg * ldb + (size_t)k0 * 2 + sslot, bB + c * 4096);
    }
  };

  auto compute = [&](int buf) {
    const char* Ab = (const char*)Alds[buf];
    const char* Bb = (const char*)Blds[buf];
    short8 af[2][4], bfr[2][2];
#pragma unroll
    for (int kk = 0; kk < 2; ++kk) {
#pragma unroll
      for (int f = 0; f < 4; ++f) {
        int rA = wm + f * 16 + (lane & 15);
        int sl = ((kk * 4 + (lane >> 4)) ^ (rA & 7)) * 16;
        af[kk][f] = *(const short8*)(Ab + (size_t)rA * 128 + sl);
      }
#pragma unroll
      for (int f = 0; f < 2; ++f) {
        int rB = wn + f * 16 + (lane & 15);
        int sl = ((kk * 4 + (lane >> 4)) ^ (rB & 7)) * 16;
        bfr[kk][f] = *(const short8*)(Bb + (size_t)rB * 128 + sl);
      }
    }
#pragma unroll
    for (int kk = 0; kk < 2; ++kk)
#pragma unroll
      for (int x = 0; x < 4; ++x)
#pragma unroll
        for (int y = 0; y < 2; ++y)
          acc[x][y] = __builtin_amdgcn_mfma_f32_16x16x32_bf16(af[kk][x], bfr[kk][y],
                                                              acc[x][y], 0, 0, 0);
  };

  const int kbeg = blockIdx.z * KC;
  const int nt = KC >> 6;
  stage(0, kbeg);
  for (int t = 0; t < nt; ++t) {
    if (t + 1 < nt) {
      stage((t + 1) & 1, kbeg + (t + 1) * 64);
      asm volatile("s_waitcnt vmcnt(6)" ::: "memory");  // tile t landed; t+1 in flight
    } else {
      asm volatile("s_waitcnt vmcnt(0)" ::: "memory");
    }
    __builtin_amdgcn_s_barrier();   // all waves' tile-t loads landed
    compute(t & 1);
    __builtin_amdgcn_s_barrier();   // readers done before next stage overwrites
  }

  if (EPI == 0) {
#pragma unroll
    for (int x = 0; x < 4; ++x) {
      int rb = m0 + wm + x * 16 + (lane >> 4) * 4;
#pragma unroll
      for (int r = 0; r < 4; ++r) {
        int row = rb + r;
        if (row < Mv) {
#pragma unroll
          for (int y = 0; y < 2; ++y)
            atomicAdd(&Cf[(size_t)row * N + (n0 + wn + y * 16 + (lane & 15))],
                      acc[x][y][r]);
        }
      }
    }
  } else if (EPI == 1) {
#pragma unroll
    for (int x = 0; x < 4; ++x) {
      int rb = m0 + wm + x * 16 + (lane >> 4) * 4;
#pragma unroll
      for (int r = 0; r < 4; ++r) {
        int row = rb + r;
#pragma unroll
        for (int y = 0; y < 2; ++y) {
          int col = n0 + wn + y * 16 + (lane & 15);
          Cb[(size_t)row * N + col] = f2bf(fmaxf(acc[x][y][r] + bias[col], 0.f));
        }
      }
    }
  } else {
    const int cnt = Mv;
#pragma unroll
    for (int x = 0; x < 4; ++x) {
      int rb = m0 + wm + x * 16 + (lane >> 4) * 4;
      int b0 = batchC[rb], b1 = batchC[rb + 1], b2 = batchC[rb + 2], b3 = batchC[rb + 3];
      float mk0 = (rb     < cnt) ? 1.f : 0.f;
      float mk1 = (rb + 1 < cnt) ? 1.f : 0.f;
      float mk2 = (rb + 2 < cnt) ? 1.f : 0.f;
      float mk3 = (rb + 3 < cnt) ? 1.f : 0.f;
#pragma unroll
      for (int y = 0; y < 2; ++y) {
        int coll = wn + y * 16 + (lane & 15);
        float bs = bias[n0 + coll];
        float s0 = mk0 * fmaxf(acc[x][y][0] + bs, 0.f);
        float s1 = mk1 * fmaxf(acc[x][y][1] + bs, 0.f);
        float s2 = mk2 * fmaxf(acc[x][y][2] + bs, 0.f);
        float s3 = mk3 * fmaxf(acc[x][y][3] + bs, 0.f);
        if (b0 == b3) {
          atomicAdd(&Gpart[b0 * 64 + coll], s0 + s1 + s2 + s3);
        } else {
          atomicAdd(&Gpart[b0 * 64 + coll], s0);
          atomicAdd(&Gpart[b1 * 64 + coll], s1);
          atomicAdd(&Gpart[b2 * 64 + coll], s2);
          atomicAdd(&Gpart[b3 * 64 + coll], s3);
        }
      }
    }
    __syncthreads();
    for (int t2 = tid; t2 < Bn * 64; t2 += 256) {
      float v = Gpart[t2];
      if (v != 0.f) atomicAdd(&G[(t2 >> 6) * LINn + n0 + (t2 & 63)], v);
    }
  }
}

// S[b][n] += sum_{k in 32-chunk} G[b][k]*Wf1[k][n]. grid (16,32), block 512.
// Widened from (16,8): 512 blocks fill the chip; serial chain 128 -> 32 MACs.
__global__ void k_final1(const float* __restrict__ G, const float* __restrict__ Wf1,
                         float* __restrict__ S) {
  __shared__ float g[32];
  int b = blockIdx.x, kz = blockIdx.y, tid = threadIdx.x;
  if (tid < 32) g[tid] = G[b * 1024 + kz * 32 + tid];
  __syncthreads();
  float acc = 0.f;
  const float* W = Wf1 + (size_t)(kz * 32) * 512 + tid;
#pragma unroll
  for (int k = 0; k < 32; ++k) acc += g[k] * W[(size_t)k * 512];
  atomicAdd(&S[b * 512 + tid], acc);
}

// out[b] = relu(S[b]+bf1) @ Wf2 + bf2. grid 16, block 256.
__global__ void k_final2(const float* __restrict__ S, const float* __restrict__ bf1,
                         const float* __restrict__ Wf2, const float* __restrict__ bf2,
                         float* __restrict__ out) {
  __shared__ float mid[512];
  __shared__ float part[256];
  int b = blockIdx.x, tid = threadIdx.x;
  for (int t = tid; t < 512; t += 256) mid[t] = fmaxf(S[b * 512 + t] + bf1[t], 0.f);
  __syncthreads();
  int o = tid & 15, seg = tid >> 4;
  float s = 0.f;
#pragma unroll
  for (int t = 0; t < 32; ++t) {
    int j = seg * 32 + t;
    s += mid[j] * Wf2[j * 16 + o];
  }
  part[tid] = s;
  __syncthreads();
  if (tid < 16) {
    float v = bf2[tid];
#pragma unroll
    for (int sg = 0; sg < 16; ++sg) v += part[sg * 16 + tid];
    out[b * 16 + tid] = v;
  }
}

extern "C" void kernel_launch(void* const* d_in, const int* in_sizes, int n_in,
                              void* d_out, int out_size, void* d_ws, size_t ws_size,
                              hipStream_t stream) {
  const float* box_feats  = (const float*)d_in[2];
  const float* q_feats    = (const float*)d_in[3];
  const float* box_coords = (const float*)d_in[4];
  const int*   index      = (const int*)d_in[5];
  const float* W1  = (const float*)d_in[6];
  const float* b1  = (const float*)d_in[7];
  const float* W2  = (const float*)d_in[8];
  const float* b2  = (const float*)d_in[9];
  const float* W3  = (const float*)d_in[10];
  const float* b3  = (const float*)d_in[11];
  const float* Wf1 = (const float*)d_in[12];
  const float* bf1 = (const float*)d_in[13];
  const float* Wf2 = (const float*)d_in[14];
  const float* bf2 = (const float*)d_in[15];
  float* out = (float*)d_out;

  char* ws = (char*)d_ws;
  size_t off = 0;
  auto alloc = [&](size_t bytes) { void* p = ws + off; off += (bytes + 255) & ~(size_t)255; return p; };
  u16* W1abT = (u16*)alloc((size_t)2048 * 2048 * 2);
  u16* W2T   = (u16*)alloc((size_t)1024 * 1024 * 2);
  u16* W3T   = (u16*)alloc((size_t)1024 * 1024 * 2);
  u16* BFb   = (u16*)alloc((size_t)NBIn * Cn * 2);
  float* P12  = (float*)alloc((size_t)640 * 2048 * 4);
  float* Pc   = (float*)alloc((size_t)Bn * LINn * 4);
  float* dotC = (float*)alloc((size_t)NPAIRn * 4);
  float* iouC = (float*)alloc((size_t)NPAIRn * 4);
  float* oijC = (float*)alloc((size_t)NPAIRn * 4);
  float* ojiC = (float*)alloc((size_t)NPAIRn * 4);
  int* pairList = (int*)alloc((size_t)(NPAIRn + 256) * 4);
  int* batchC   = (int*)alloc((size_t)(NPAIRn + 256) * 4);
  int* cnt2     = (int*)alloc(64);
  float* G  = (float*)alloc((size_t)Bn * LINn * 4);
  float* S  = (float*)alloc((size_t)Bn * 512 * 4);
  u16* H1 = (u16*)alloc((size_t)NPAIRn * 1024 * 2);
  u16* H2 = (u16*)alloc((size_t)NPAIRn * 1024 * 2);

  // Fused prep: transposes + f2b + zero-init + pair-list build
  k_prep<<<dim3(32, 64, 6), 256, 0, stream>>>(W1, W2, W3, box_feats, index,
                                              W1abT, W2T, W3T, BFb,
                                              pairList, batchC, cnt2, G, S, Pc);
  k_pconst<<<dim3(4, 32), 256, 0, stream>>>(q_feats, W1, Pc);
  // Fused mid: pair scalars (blocks 0..647) + P12 init (blocks 648..1223)
  k_mid<<<1224, 256, 0, stream>>>(box_feats, box_coords, pairList, cnt2, Pc, b1, W1,
                                  dotC, iouC, oijC, ojiC, P12);
  // P-GEMM atomically accumulates BFb @ [W1a|W1b] onto the initialized P12
  k_gemm<0><<<dim3(5, 32, 4), 256, 0, stream>>>(BFb, W1abT, 2048, 2048, 512, NBIn, nullptr,
                                                P12, nullptr, nullptr, nullptr, nullptr);
  k_h1<<<2592, 256, 0, stream>>>(P12, dotC, iouC, oijC, ojiC, pairList, cnt2, W1, H1);
  // H2 = relu(H1 @ W2 + b2)   (1D grid, XCD-affine remap inside)
  k_gemm<1><<<dim3(2592, 1, 1), 256, 0, stream>>>(H1, W2T, 1024, 1024, 1024, 0, cnt2,
                                                  nullptr, H2, b2, nullptr, nullptr);
  // G[b] += relu(H2 @ W3 + b3)  (fused masked pair-reduction)
  k_gemm<2><<<dim3(2592, 1, 1), 256, 0, stream>>>(H2, W3T, 1024, 1024, 1024, 0, cnt2,
                                                  nullptr, nullptr, b3, batchC, G);
  k_final1<<<dim3(16, 32), 512, 0, stream>>>(G, Wf1, S);
  k_final2<<<16, 256, 0, stream>>>(S, bf1, Wf2, bf2, out);
}